// Round 7
// baseline (863.979 us; speedup 1.0000x reference)
//
#include <hip/hip_runtime.h>
#include <hip/hip_bf16.h>

#define BD 2
#define HD 480
#define WD 480
#define CD 32
#define HALFD 16
#define WND 20
#define NP 500
#define PLANE (HD*WD)
#define TWO_PI_OVER_NP 0.012566370614359172954f  /* 2*pi/500 */

typedef __attribute__((ext_vector_type(8))) short bf16x8;
typedef __attribute__((ext_vector_type(4))) float f32x4;

__device__ __forceinline__ float gelu_f(float x) {
    return 0.5f * x * (1.0f + erff(x * 0.70710678118654752f));
}
__device__ __forceinline__ short bf16s(float v) {
    __hip_bfloat16 b = __float2bfloat16(v);
    return *reinterpret_cast<short*>(&b);
}

// Input MLP for a: MLP 5->16->32 on (src, grid). Channel-planar bf16 (B,C,H,W).
__global__ void __launch_bounds__(256) k_ae(
    const float* src,
    const float* iw1, const float* ib1,
    const float* iw2, const float* ib2,
    __hip_bfloat16* A)
{
    __shared__ float s_iw1[80], s_ib1[16], s_iw2[512], s_ib2[32];
    int tid = threadIdx.x;
    for (int t = tid; t < 512; t += 256) s_iw2[t] = iw2[t];
    if (tid < 80) s_iw1[tid] = iw1[tid];
    if (tid >= 96 && tid < 112) s_ib1[tid - 96] = ib1[tid - 96];
    if (tid >= 128 && tid < 160) s_ib2[tid - 128] = ib2[tid - 128];
    __syncthreads();
    int gid = blockIdx.x * 256 + tid;  // < 460800
    int b = gid / PLANE;
    int r = gid % PLANE;
    int h = r / WD, w = r % WD;
    float gx = (float)h * (1.0f / 479.0f);
    float gy = (float)w * (1.0f / 479.0f);
    float s0 = src[(size_t)gid * 3 + 0];
    float s1 = src[(size_t)gid * 3 + 1];
    float s2 = src[(size_t)gid * 3 + 2];
    float hid[16];
    #pragma unroll
    for (int j = 0; j < 16; j++) {
        float v = s_ib1[j] + s0 * s_iw1[j] + s1 * s_iw1[16 + j] + s2 * s_iw1[32 + j]
                + gx * s_iw1[48 + j] + gy * s_iw1[64 + j];
        hid[j] = gelu_f(v);
    }
    __hip_bfloat16* Ap = A + (size_t)b * CD * PLANE + r;
    for (int c = 0; c < 32; c++) {
        float v = s_ib2[c];
        #pragma unroll
        for (int j = 0; j < 16; j++) v += hid[j] * s_iw2[j * 32 + c];
        Ap[(size_t)c * PLANE] = __float2bfloat16(v);
    }
}

// Swizzled bf16 twiddle fragments for the F1 row-DFT GEMM (K=480, N=48 pad).
__global__ void k_twig(__hip_bfloat16* Twig) {
    int e = blockIdx.x * 256 + threadIdx.x;   // < 45*512
    if (e >= 45 * 512) return;
    int tile = e >> 9, r = e & 511;
    int lane = r >> 3, j = r & 7;
    int kt = tile / 3, nt = tile % 3;
    int k = kt * 32 + ((lane >> 4) << 3) + j;
    int n = nt * 16 + (lane & 15);
    float v = 0.0f;
    if (n < 40) {
        int ky = n >> 1;
        int idx = (k * ky) % NP;
        float ang = (float)idx * TWO_PI_OVER_NP;
        v = (n & 1) ? -sinf(ang) : cosf(ang);
    }
    Twig[e] = __float2bfloat16(v);
}

// Swizzled bf16 inverse-twiddle B-fragments for the I2 GEMM (K=64 pad, N=480).
__global__ void k_tinv(__hip_bfloat16* TinvF) {
    int e = blockIdx.x * 256 + threadIdx.x;   // < 60*512
    if (e >= 60 * 512) return;
    int tile = e >> 9, r = e & 511;
    int lane = r >> 3, j = r & 7;
    int nt = tile >> 1, kt = tile & 1;
    int kk = kt * 32 + ((lane >> 4) << 3) + j;
    int w = nt * 16 + (lane & 15);
    float v = 0.0f;
    if (kk < 40) {
        int ky = kk >> 1;
        int idx = (ky * w) % NP;
        float ang = (float)idx * TWO_PI_OVER_NP;
        v = (kk & 1) ? -sinf(ang) : cosf(ang);
    }
    TinvF[e] = __float2bfloat16(v);
}

// Swizzled bf16 B-fragments for the F2 h-DFT GEMM.
// Y2[m][n] = sum_k Y1row[m][k] * B[k][n]; k=2h+ri (ri0=re,ri1=im),
// n=2kxi+part: part0: (re*cos + im*sin); part1: (im*cos - re*sin).
__global__ void k_tf2(__hip_bfloat16* Tf2) {
    int e = blockIdx.x * 256 + threadIdx.x;   // < 150*512
    if (e >= 150 * 512) return;
    int tile = e >> 9, r = e & 511;
    int lane = r >> 3, j = r & 7;
    int kt = tile / 5, nt = tile % 5;
    int k = kt * 32 + ((lane >> 4) << 3) + j;
    int n = nt * 16 + (lane & 15);
    int hh = k >> 1, ri = k & 1;
    int kxi = n >> 1, part = n & 1;
    int kx = (kxi < 20) ? kxi : kxi + 460;
    int idx = (kx * hh) % NP;
    float ang = (float)idx * TWO_PI_OVER_NP;
    float c = cosf(ang), s = sinf(ang);
    float v = (part == 0) ? (ri == 0 ? c : s) : (ri == 0 ? -s : c);
    Tf2[e] = __float2bfloat16(v);
}

// F1 (used once, for the initial A): block per (b,h); e-MLP + g=a*e staged in
// LDS, then row-DFT as MFMA GEMM against Twig.
__global__ void __launch_bounds__(256) k_F1g(
    const __hip_bfloat16* A, const float* inp,
    const float* ew1, const float* eb1,
    const float* ew2, const float* eb2,
    const __hip_bfloat16* Twig,
    __hip_bfloat16* Y1)
{
    __shared__ __hip_bfloat16 G[32][488];
    __shared__ float s_ew1[48], s_eb1[16], s_ew2[512], s_eb2[32];
    int tid = threadIdx.x;
    for (int t = tid; t < 512; t += 256) s_ew2[t] = ew2[t];
    if (tid < 48) s_ew1[tid] = ew1[tid];
    if (tid >= 64 && tid < 80) s_eb1[tid - 64] = eb1[tid - 64];
    if (tid >= 96 && tid < 128) s_eb2[tid - 96] = eb2[tid - 96];
    __syncthreads();
    int b = blockIdx.x / HD;
    int h = blockIdx.x % HD;
    float gx = (float)h * (1.0f / 479.0f);
    const __hip_bfloat16* Abase = A + ((size_t)b * CD) * PLANE + (size_t)h * WD;
    for (int w = tid; w < WD; w += 256) {
        float xi = inp[(size_t)b * PLANE + (size_t)h * WD + w];
        float gy = (float)w * (1.0f / 479.0f);
        float hid[16];
        #pragma unroll
        for (int j = 0; j < 16; j++) {
            float v = s_eb1[j] + xi * s_ew1[j] + gx * s_ew1[16 + j] + gy * s_ew1[32 + j];
            hid[j] = gelu_f(v);
        }
        #pragma unroll
        for (int c = 0; c < 32; c++) {
            float e = s_eb2[c];
            #pragma unroll
            for (int j = 0; j < 16; j++) e += hid[j] * s_ew2[j * 32 + c];
            float a = __bfloat162float(Abase[(size_t)c * PLANE + w]);
            G[c][w] = __float2bfloat16(e * a);
        }
    }
    __syncthreads();
    int wv = tid >> 6, lane = tid & 63;
    int arow_lo = lane & 15;
    int kofs = (lane >> 4) << 3;
    for (int t = wv; t < 6; t += 4) {
        int mt = t & 1, nt = t >> 1;
        f32x4 acc = {0.f, 0.f, 0.f, 0.f};
        int arow = mt * 16 + arow_lo;
        #pragma unroll
        for (int kt = 0; kt < 15; kt++) {
            bf16x8 av = *reinterpret_cast<const bf16x8*>(&G[arow][kt * 32 + kofs]);
            bf16x8 bv = *reinterpret_cast<const bf16x8*>(Twig + (((kt * 3 + nt) << 9) + lane * 8));
            acc = __builtin_amdgcn_mfma_f32_16x16x32_bf16(av, bv, acc, 0, 0, 0);
        }
        int n = nt * 16 + (lane & 15);
        if (n < 40) {
            int ky = n >> 1, part = n & 1;
            int crow = mt * 16 + ((lane >> 4) << 2);
            #pragma unroll
            for (int r = 0; r < 4; r++) {
                int c = crow + r;
                Y1[((((size_t)(b * 32 + c)) * WND + ky) * HD + h) * 2 + part] =
                    __float2bfloat16(acc[r]);
            }
        }
    }
}

// F2 as MFMA GEMM: M=1280 rows (bc*20+ky, contiguous 960 bf16 each in Y1),
// K=960, N=80. One wave per (M-tile, N-tile); 30 K-step MFMAs.
__global__ void __launch_bounds__(256) k_F2m(
    const __hip_bfloat16* Y1, const __hip_bfloat16* Tf2, float* Y2)
{
    int wv = threadIdx.x >> 6, lane = threadIdx.x & 63;
    int task = blockIdx.x * 4 + wv;          // < 400
    int mt = task / 5, nt = task % 5;
    int row = mt * 16 + (lane & 15);
    int koff = (lane >> 4) << 3;
    const __hip_bfloat16* arow = Y1 + (size_t)row * 960 + koff;
    f32x4 acc = {0.f, 0.f, 0.f, 0.f};
    #pragma unroll
    for (int kt = 0; kt < 30; kt++) {
        bf16x8 av = *reinterpret_cast<const bf16x8*>(arow + kt * 32);
        bf16x8 bv = *reinterpret_cast<const bf16x8*>(Tf2 + (((kt * 5 + nt) << 9) + lane * 8));
        acc = __builtin_amdgcn_mfma_f32_16x16x32_bf16(av, bv, acc, 0, 0, 0);
    }
    int n = nt * 16 + (lane & 15);
    int mb = mt * 16 + ((lane >> 4) << 2);
    #pragma unroll
    for (int r = 0; r < 4; r++)
        Y2[(size_t)(mb + r) * 80 + n] = acc[r];
}

// Per-frequency channel mixing (real and imag independently).
__global__ void __launch_bounds__(256) k_mix(
    const float* Y2, float* Z,
    const float* fw1, const float* fw2, int l)
{
    int gid = blockIdx.x * 256 + threadIdx.x;  // < 102400
    int z = gid & 1;
    int kxi = (gid >> 1) % 40;
    int ky = (gid / 80) % 20;
    int oc = (gid / 1600) % 32;
    int b = gid / 51200;
    const float* wp;
    int x;
    if (kxi < 20) { wp = fw1; x = kxi; } else { wp = fw2; x = kxi - 20; }
    size_t wbase = ((((size_t)(l * 32) * 32 + oc) * 20 + x) * 20 + ky) * 2 + z;
    const float* y2 = Y2 + (((size_t)b * 32 * 20 + ky) * 40 + kxi) * 2 + z;
    float acc = 0.f;
    for (int i = 0; i < 32; i++) {
        float yv = y2[(size_t)i * 1600];
        float wv = wp[wbase + (size_t)i * 25600];
        acc += yv * wv;
    }
    Z[((((size_t)b * 32 + oc) * 20 + ky) * 40 + kxi) * 2 + z] = acc;
}

// I1: inverse complex DFT over kx -> h. U[b,o,ky,h] complex bf16 (unscaled).
__global__ void __launch_bounds__(256) k_I1(
    const float* Z, __hip_bfloat16* U)
{
    __shared__ float sC[NP], sS[NP];
    int tid = threadIdx.x;
    for (int t = tid; t < NP; t += 256) {
        float ang = (float)t * TWO_PI_OVER_NP;
        sC[t] = cosf(ang);
        sS[t] = sinf(ang);
    }
    __syncthreads();
    int gid = blockIdx.x * 256 + tid;  // < 614400
    int h = gid % HD;
    int ky = (gid / HD) % 20;
    int bo = gid / (HD * 20);
    const float2* zp = reinterpret_cast<const float2*>(Z) + ((size_t)bo * WND + ky) * 40;
    float ar = 0.f, ai = 0.f;
    int idx = 0;
    #pragma unroll
    for (int j = 0; j < 20; j++) {
        float2 zz = zp[j];
        float cv = sC[idx], sv = sS[idx];
        ar += zz.x * cv - zz.y * sv;
        ai += zz.x * sv + zz.y * cv;
        idx += h; if (idx >= NP) idx -= NP;
    }
    idx = (480 * h) % NP;
    #pragma unroll
    for (int j = 20; j < 40; j++) {
        float2 zz = zp[j];
        float cv = sC[idx], sv = sS[idx];
        ar += zz.x * cv - zz.y * sv;
        ai += zz.x * sv + zz.y * cv;
        idx += h; if (idx >= NP) idx -= NP;
    }
    __hip_bfloat162 v;
    v.x = __float2bfloat16(ar);
    v.y = __float2bfloat16(ai);
    reinterpret_cast<__hip_bfloat162*>(U)[((size_t)bo * WND + ky) * HD + h] = v;
}

// Fused I2 + next-layer F1. Per (b,h) row:
//   Anew[oc][w] = act( U-DFT + 1x1 conv + bias )   (in-place A update)
//   if do_dft:  G = Anew * e  (e-MLP staged in Elds), row-DFT GEMM -> Y1.
// LDS: sBfG (Ain B-frags, reused post-barrier as G[32][480]) + Elds + weights
// = 64,000 B. U/convW A-operand fragments live in registers (built from
// global before the barrier; U column h is re-written as Y1 column h later,
// same block only -> safe).
__global__ void __launch_bounds__(256) k_I2F1(
    const __hip_bfloat16* U, __hip_bfloat16* A, __hip_bfloat16* Y1,
    const float* convw, const float* convb,
    const __hip_bfloat16* TinvF, const __hip_bfloat16* Twig,
    const float* inp,
    const float* ew1, const float* eb1, const float* ew2, const float* eb2,
    int l, int do_gelu, int do_dft)
{
    __shared__ __align__(16) __hip_bfloat16 sBfG[15360];  // 30 tiles*512 | G[32][480]
    __shared__ __align__(16) __hip_bfloat16 Elds[15360];  // e[32][480]
    __shared__ float s_ew1[48], s_eb1[16], s_ew2[512], s_eb2[32];
    __shared__ float sB[32];
    int tid = threadIdx.x;
    int b = blockIdx.x / HD, h = blockIdx.x % HD;
    int wv = tid >> 6, lane = tid & 63;
    int mrow = lane & 15;
    int koff = (lane >> 4) << 3;

    for (int t = tid; t < 512; t += 256) s_ew2[t] = ew2[t];
    if (tid < 48) s_ew1[tid] = ew1[tid];
    if (tid >= 64 && tid < 80) s_eb1[tid - 64] = eb1[tid - 64];
    if (tid >= 96 && tid < 128) s_eb2[tid - 96] = eb2[tid - 96];
    if (tid >= 128 && tid < 160) sB[tid - 128] = convb[l * 32 + (tid - 128)];

    // register A-operand fragments: U (2 mt x 2 kt) and convW (2 mt)
    bf16x8 uf[2][2], wf[2];
    {
        const __hip_bfloat162* U2 = reinterpret_cast<const __hip_bfloat162*>(U);
        #pragma unroll
        for (int mt = 0; mt < 2; mt++) {
            int oc = mt * 16 + mrow;
            #pragma unroll
            for (int kt = 0; kt < 2; kt++) {
                bf16x8 v;
                #pragma unroll
                for (int j = 0; j < 8; j++) {
                    int kk = kt * 32 + koff + j;
                    float val = 0.f;
                    if (kk < 40) {
                        int ky = kk >> 1;
                        __hip_bfloat162 u = U2[((size_t)(b * 32 + oc) * WND + ky) * HD + h];
                        float sc = (ky == 0 ? 1.0f : 2.0f) * (1.0f / 250000.0f);
                        val = ((kk & 1) ? __bfloat162float(u.y) : __bfloat162float(u.x)) * sc;
                    }
                    v[j] = bf16s(val);
                }
                uf[mt][kt] = v;
            }
            bf16x8 wvv;
            #pragma unroll
            for (int j = 0; j < 8; j++)
                wvv[j] = bf16s(convw[(size_t)l * 1024 + oc * 32 + koff + j]);
            wf[mt] = wvv;
        }
    }
    // Ain B-fragments (reads A BEFORE the in-place overwrite)
    {
        const unsigned short* Ab = reinterpret_cast<const unsigned short*>(
            A + (size_t)b * CD * PLANE + (size_t)h * WD);
        for (int w = tid; w < WD; w += 256) {
            unsigned short vals[32];
            #pragma unroll
            for (int ic = 0; ic < 32; ic++)
                vals[ic] = Ab[(size_t)ic * PLANE + w];
            int nt = w >> 4, lw = w & 15;
            #pragma unroll
            for (int q = 0; q < 4; q++) {
                uint4 pk;
                pk.x = (unsigned)vals[8 * q + 0] | ((unsigned)vals[8 * q + 1] << 16);
                pk.y = (unsigned)vals[8 * q + 2] | ((unsigned)vals[8 * q + 3] << 16);
                pk.z = (unsigned)vals[8 * q + 4] | ((unsigned)vals[8 * q + 5] << 16);
                pk.w = (unsigned)vals[8 * q + 6] | ((unsigned)vals[8 * q + 7] << 16);
                *reinterpret_cast<uint4*>(&sBfG[(nt << 9) + (((q << 4) | lw) << 3)]) = pk;
            }
        }
    }
    __syncthreads();   // s_ew* ready below, sBfG ready
    // e-MLP into Elds (needed only if we run the DFT)
    if (do_dft) {
        float gx = (float)h * (1.0f / 479.0f);
        for (int w = tid; w < WD; w += 256) {
            float xi = inp[(size_t)b * PLANE + (size_t)h * WD + w];
            float gy = (float)w * (1.0f / 479.0f);
            float hid[16];
            #pragma unroll
            for (int j = 0; j < 16; j++) {
                float v = s_eb1[j] + xi * s_ew1[j] + gx * s_ew1[16 + j] + gy * s_ew1[32 + j];
                hid[j] = gelu_f(v);
            }
            #pragma unroll
            for (int c = 0; c < 32; c++) {
                float e = s_eb2[c];
                #pragma unroll
                for (int j = 0; j < 16; j++) e += hid[j] * s_ew2[j * 32 + c];
                Elds[c * 480 + w] = __float2bfloat16(e);
            }
        }
    }
    // MFMA: 60 tiles over 4 waves, accumulators held in registers
    f32x4 accs[15];
    #pragma unroll
    for (int i = 0; i < 15; i++) {
        int t = wv + 4 * i;
        int mt = t & 1, nt = t >> 1;
        f32x4 acc = {0.f, 0.f, 0.f, 0.f};
        #pragma unroll
        for (int kt = 0; kt < 2; kt++) {
            bf16x8 bvv = *reinterpret_cast<const bf16x8*>(TinvF + (((nt * 2 + kt) << 9) + lane * 8));
            acc = __builtin_amdgcn_mfma_f32_16x16x32_bf16(uf[mt][kt], bvv, acc, 0, 0, 0);
        }
        bf16x8 bv2 = *reinterpret_cast<const bf16x8*>(&sBfG[(nt << 9) + lane * 8]);
        acc = __builtin_amdgcn_mfma_f32_16x16x32_bf16(wf[mt], bv2, acc, 0, 0, 0);
        accs[i] = acc;
    }
    __syncthreads();   // all sBfG reads done; safe to overwrite with G
    // epilogue: bias + gelu, write A, stage G = Anew * e
    #pragma unroll
    for (int i = 0; i < 15; i++) {
        int t = wv + 4 * i;
        int mt = t & 1, nt = t >> 1;
        int w = nt * 16 + (lane & 15);
        int ocb = mt * 16 + ((lane >> 4) << 2);
        #pragma unroll
        for (int r = 0; r < 4; r++) {
            float v = accs[i][r] + sB[ocb + r];
            if (do_gelu) v = gelu_f(v);
            A[((size_t)b * CD + (ocb + r)) * PLANE + (size_t)h * WD + w] = __float2bfloat16(v);
            if (do_dft) {
                float e = __bfloat162float(Elds[(ocb + r) * 480 + w]);
                sBfG[(ocb + r) * 480 + w] = __float2bfloat16(v * e);
            }
        }
    }
    if (do_dft) {
        __syncthreads();
        // forward row-DFT GEMM: G[32][480] x Twig -> Y1 column h
        for (int t = wv; t < 6; t += 4) {
            int mt = t & 1, nt = t >> 1;
            f32x4 acc = {0.f, 0.f, 0.f, 0.f};
            int arow = mt * 16 + mrow;
            #pragma unroll
            for (int kt = 0; kt < 15; kt++) {
                bf16x8 av = *reinterpret_cast<const bf16x8*>(&sBfG[arow * 480 + kt * 32 + koff]);
                bf16x8 bvv = *reinterpret_cast<const bf16x8*>(Twig + (((kt * 3 + nt) << 9) + lane * 8));
                acc = __builtin_amdgcn_mfma_f32_16x16x32_bf16(av, bvv, acc, 0, 0, 0);
            }
            int n = nt * 16 + (lane & 15);
            if (n < 40) {
                int ky = n >> 1, part = n & 1;
                int crow = mt * 16 + ((lane >> 4) << 2);
                #pragma unroll
                for (int r = 0; r < 4; r++) {
                    int c = crow + r;
                    Y1[((((size_t)(b * 32 + c)) * WND + ky) * HD + h) * 2 + part] =
                        __float2bfloat16(acc[r]);
                }
            }
        }
    }
}

// Final: proj MLP + 3x3 mask conv + field*mask + pred.
__global__ void __launch_bounds__(256) k_out(
    const __hip_bfloat16* Afin, const float* inp, const float* src,
    const float* pw1, const float* pb1,
    const float* pw2, const float* pb2,
    const float* mw, const float* mb,
    float* out)
{
    __shared__ float sW1[CD * HALFD], sB1[HALFD], sW2[HALFD * 2], sB2[2], sM[9], sMB[1];
    int tid = threadIdx.x;
    for (int t = tid; t < CD * HALFD; t += 256) sW1[t] = pw1[t];
    if (tid < 16) sB1[tid] = pb1[tid];
    if (tid >= 32 && tid < 64) sW2[tid - 32] = pw2[tid - 32];
    if (tid >= 64 && tid < 66) sB2[tid - 64] = pb2[tid - 64];
    if (tid >= 96 && tid < 105) sM[tid - 96] = mw[tid - 96];
    if (tid == 128) sMB[0] = mb[0];
    __syncthreads();
    int gid = blockIdx.x * 256 + tid;  // < 460800
    int b = gid / PLANE;
    int r = gid % PLANE;
    int h = r / WD, w = r % WD;
    const __hip_bfloat16* ap = Afin + (size_t)b * CD * PLANE + r;
    float av[32];
    #pragma unroll
    for (int i = 0; i < 32; i++) av[i] = __bfloat162float(ap[(size_t)i * PLANE]);
    float hid[16];
    #pragma unroll
    for (int j = 0; j < 16; j++) {
        float v = sB1[j];
        #pragma unroll
        for (int i = 0; i < 32; i++) v += av[i] * sW1[i * 16 + j];
        hid[j] = gelu_f(v);
    }
    float p0 = sB2[0], p1 = sB2[1];
    #pragma unroll
    for (int j = 0; j < 16; j++) { p0 += hid[j] * sW2[j * 2]; p1 += hid[j] * sW2[j * 2 + 1]; }
    float m = sMB[0];
    #pragma unroll
    for (int dh = 0; dh < 3; dh++) {
        int hh = h + dh - 1;
        #pragma unroll
        for (int dw = 0; dw < 3; dw++) {
            int ww = w + dw - 1;
            if (hh >= 0 && hh < HD && ww >= 0 && ww < WD)
                m += inp[(size_t)b * PLANE + (size_t)hh * WD + ww] * sM[dh * 3 + dw];
        }
    }
    float f0 = src[(size_t)gid * 3 + 1];
    float f1 = src[(size_t)gid * 3 + 2];
    out[(size_t)gid * 2 + 0] = f0 * m + p0;
    out[(size_t)gid * 2 + 1] = f1 * m + p1;
}

extern "C" void kernel_launch(void* const* d_in, const int* in_sizes, int n_in,
                              void* d_out, int out_size, void* d_ws, size_t ws_size,
                              hipStream_t stream) {
    const float* inp = (const float*)d_in[0];
    const float* src = (const float*)d_in[1];
    const float* iw1 = (const float*)d_in[2];
    const float* ib1 = (const float*)d_in[3];
    const float* iw2 = (const float*)d_in[4];
    const float* ib2 = (const float*)d_in[5];
    const float* ew1 = (const float*)d_in[6];
    const float* eb1 = (const float*)d_in[7];
    const float* ew2 = (const float*)d_in[8];
    const float* eb2 = (const float*)d_in[9];
    const float* fw1 = (const float*)d_in[10];
    const float* fw2 = (const float*)d_in[11];
    const float* cw  = (const float*)d_in[12];
    const float* cb  = (const float*)d_in[13];
    const float* pw1 = (const float*)d_in[14];
    const float* pb1 = (const float*)d_in[15];
    const float* pw2 = (const float*)d_in[16];
    const float* pb2 = (const float*)d_in[17];
    const float* mw  = (const float*)d_in[18];
    const float* mb  = (const float*)d_in[19];

    // Workspace (~33.1 MB): A bf16 | Y1U bf16 (Y1<->U aliased) | Y2 f32 | Z f32
    //                       | Twig | TinvF | Tf2 (bf16 fragment tables)
    const size_t NA = (size_t)BD * CD * PLANE;
    __hip_bfloat16* A   = (__hip_bfloat16*)d_ws;
    __hip_bfloat16* Y1U = A + NA;
    float* Y2 = (float*)(Y1U + (size_t)BD * CD * WND * HD * 2);
    float* Z  = Y2 + (size_t)BD * CD * WND * 40 * 2;
    __hip_bfloat16* Twig  = (__hip_bfloat16*)(Z + (size_t)BD * CD * WND * 40 * 2);
    __hip_bfloat16* TinvF = Twig + 45 * 512;
    __hip_bfloat16* Tf2   = TinvF + 60 * 512;

    k_twig<<<90, 256, 0, stream>>>(Twig);
    k_tinv<<<120, 256, 0, stream>>>(TinvF);
    k_tf2<<<300, 256, 0, stream>>>(Tf2);
    k_ae<<<1800, 256, 0, stream>>>(src, iw1, ib1, iw2, ib2, A);
    k_F1g<<<BD * HD, 256, 0, stream>>>(A, inp, ew1, eb1, ew2, eb2, Twig, Y1U);

    for (int l = 0; l < 4; l++) {
        k_F2m<<<100, 256, 0, stream>>>(Y1U, Tf2, Y2);
        k_mix<<<400, 256, 0, stream>>>(Y2, Z, fw1, fw2, l);
        k_I1<<<2400, 256, 0, stream>>>(Z, Y1U);
        k_I2F1<<<BD * HD, 256, 0, stream>>>(Y1U, A, Y1U, cw, cb, TinvF, Twig,
                                            inp, ew1, eb1, ew2, eb2,
                                            l, (l < 3) ? 1 : 0, (l < 3) ? 1 : 0);
    }
    k_out<<<1800, 256, 0, stream>>>(A, inp, src, pw1, pb1, pw2, pb2, mw, mb,
                                    (float*)d_out);
}

// Round 8
// 617.959 us; speedup vs baseline: 1.3981x; 1.3981x over previous
//
#include <hip/hip_runtime.h>
#include <hip/hip_bf16.h>

#define BD 2
#define HD 480
#define WD 480
#define CD 32
#define HALFD 16
#define WND 20
#define NP 500
#define PLANE (HD*WD)
#define TWO_PI_OVER_NP 0.012566370614359172954f  /* 2*pi/500 */

typedef __attribute__((ext_vector_type(8))) short bf16x8;
typedef __attribute__((ext_vector_type(4))) float f32x4;

__device__ __forceinline__ float gelu_f(float x) {
    return 0.5f * x * (1.0f + erff(x * 0.70710678118654752f));
}

// Input MLP for a: MLP 5->16->32 on (src, grid). Channel-planar bf16 (B,C,H,W).
__global__ void __launch_bounds__(256) k_ae(
    const float* src,
    const float* iw1, const float* ib1,
    const float* iw2, const float* ib2,
    __hip_bfloat16* A)
{
    __shared__ float s_iw1[80], s_ib1[16], s_iw2[512], s_ib2[32];
    int tid = threadIdx.x;
    for (int t = tid; t < 512; t += 256) s_iw2[t] = iw2[t];
    if (tid < 80) s_iw1[tid] = iw1[tid];
    if (tid >= 96 && tid < 112) s_ib1[tid - 96] = ib1[tid - 96];
    if (tid >= 128 && tid < 160) s_ib2[tid - 128] = ib2[tid - 128];
    __syncthreads();
    int gid = blockIdx.x * 256 + tid;  // < 460800
    int b = gid / PLANE;
    int r = gid % PLANE;
    int h = r / WD, w = r % WD;
    float gx = (float)h * (1.0f / 479.0f);
    float gy = (float)w * (1.0f / 479.0f);
    float s0 = src[(size_t)gid * 3 + 0];
    float s1 = src[(size_t)gid * 3 + 1];
    float s2 = src[(size_t)gid * 3 + 2];
    float hid[16];
    #pragma unroll
    for (int j = 0; j < 16; j++) {
        float v = s_ib1[j] + s0 * s_iw1[j] + s1 * s_iw1[16 + j] + s2 * s_iw1[32 + j]
                + gx * s_iw1[48 + j] + gy * s_iw1[64 + j];
        hid[j] = gelu_f(v);
    }
    __hip_bfloat16* Ap = A + (size_t)b * CD * PLANE + r;
    for (int c = 0; c < 32; c++) {
        float v = s_ib2[c];
        #pragma unroll
        for (int j = 0; j < 16; j++) v += hid[j] * s_iw2[j * 32 + c];
        Ap[(size_t)c * PLANE] = __float2bfloat16(v);
    }
}

// Swizzled bf16 twiddle fragments for the F1 row-DFT GEMM (K=480, N=48 pad).
__global__ void k_twig(__hip_bfloat16* Twig) {
    int e = blockIdx.x * 256 + threadIdx.x;   // < 45*512
    if (e >= 45 * 512) return;
    int tile = e >> 9, r = e & 511;
    int lane = r >> 3, j = r & 7;
    int kt = tile / 3, nt = tile % 3;
    int k = kt * 32 + ((lane >> 4) << 3) + j;
    int n = nt * 16 + (lane & 15);
    float v = 0.0f;
    if (n < 40) {
        int ky = n >> 1;
        int idx = (k * ky) % NP;
        float ang = (float)idx * TWO_PI_OVER_NP;
        v = (n & 1) ? -sinf(ang) : cosf(ang);
    }
    Twig[e] = __float2bfloat16(v);
}

// Swizzled bf16 inverse-twiddle B-fragments for the I2 GEMM (K=64 pad, N=480).
__global__ void k_tinv(__hip_bfloat16* TinvF) {
    int e = blockIdx.x * 256 + threadIdx.x;   // < 60*512
    if (e >= 60 * 512) return;
    int tile = e >> 9, r = e & 511;
    int lane = r >> 3, j = r & 7;
    int nt = tile >> 1, kt = tile & 1;
    int kk = kt * 32 + ((lane >> 4) << 3) + j;
    int w = nt * 16 + (lane & 15);
    float v = 0.0f;
    if (kk < 40) {
        int ky = kk >> 1;
        int idx = (ky * w) % NP;
        float ang = (float)idx * TWO_PI_OVER_NP;
        v = (kk & 1) ? -sinf(ang) : cosf(ang);
    }
    TinvF[e] = __float2bfloat16(v);
}

// Swizzled bf16 B-fragments for the F2 h-DFT GEMM.
// Y2[m][n] = sum_k Y1row[m][k] * B[k][n]; k=2h+ri (ri0=re,ri1=im),
// n=2kxi+part: part0: (re*cos + im*sin); part1: (im*cos - re*sin).
__global__ void k_tf2(__hip_bfloat16* Tf2) {
    int e = blockIdx.x * 256 + threadIdx.x;   // < 150*512
    if (e >= 150 * 512) return;
    int tile = e >> 9, r = e & 511;
    int lane = r >> 3, j = r & 7;
    int kt = tile / 5, nt = tile % 5;
    int k = kt * 32 + ((lane >> 4) << 3) + j;
    int n = nt * 16 + (lane & 15);
    int hh = k >> 1, ri = k & 1;
    int kxi = n >> 1, part = n & 1;
    int kx = (kxi < 20) ? kxi : kxi + 460;
    int idx = (kx * hh) % NP;
    float ang = (float)idx * TWO_PI_OVER_NP;
    float c = cosf(ang), s = sinf(ang);
    float v = (part == 0) ? (ri == 0 ? c : s) : (ri == 0 ? -s : c);
    Tf2[e] = __float2bfloat16(v);
}

// Swizzled bf16 B-fragments for the I1 inverse-kx GEMM.
// U[m][n] = sum_k Zb[m][k] * B[k][n]; k=2kxi+ri (K=80 pad 96), n=2h+part.
// re out (part0): zr*cos - zi*sin; im out (part1): zr*sin + zi*cos.
__global__ void k_ti1(__hip_bfloat16* Ti1) {
    int e = blockIdx.x * 256 + threadIdx.x;   // < 180*512
    if (e >= 180 * 512) return;
    int tile = e >> 9, r = e & 511;
    int lane = r >> 3, j = r & 7;
    int nt = tile / 3, kt = tile % 3;
    int k = kt * 32 + ((lane >> 4) << 3) + j;
    int n = nt * 16 + (lane & 15);
    float v = 0.0f;
    if (k < 80) {
        int kxi = k >> 1, ri = k & 1;
        int hh = n >> 1, part = n & 1;
        int kx = (kxi < 20) ? kxi : kxi + 460;
        int idx = (kx * hh) % NP;
        float ang = (float)idx * TWO_PI_OVER_NP;
        float c = cosf(ang), s = sinf(ang);
        v = (part == 0) ? (ri == 0 ? c : -s) : (ri == 0 ? s : c);
    }
    Ti1[e] = __float2bfloat16(v);
}

// F1: block per (b,h); e-MLP + g=a*e staged in LDS, row-DFT MFMA GEMM vs Twig.
__global__ void __launch_bounds__(256) k_F1g(
    const __hip_bfloat16* A, const float* inp,
    const float* ew1, const float* eb1,
    const float* ew2, const float* eb2,
    const __hip_bfloat16* Twig,
    __hip_bfloat16* Y1)
{
    __shared__ __hip_bfloat16 G[32][488];
    __shared__ float s_ew1[48], s_eb1[16], s_ew2[512], s_eb2[32];
    int tid = threadIdx.x;
    for (int t = tid; t < 512; t += 256) s_ew2[t] = ew2[t];
    if (tid < 48) s_ew1[tid] = ew1[tid];
    if (tid >= 64 && tid < 80) s_eb1[tid - 64] = eb1[tid - 64];
    if (tid >= 96 && tid < 128) s_eb2[tid - 96] = eb2[tid - 96];
    __syncthreads();
    int b = blockIdx.x / HD;
    int h = blockIdx.x % HD;
    float gx = (float)h * (1.0f / 479.0f);
    const __hip_bfloat16* Abase = A + ((size_t)b * CD) * PLANE + (size_t)h * WD;
    for (int w = tid; w < WD; w += 256) {
        float xi = inp[(size_t)b * PLANE + (size_t)h * WD + w];
        float gy = (float)w * (1.0f / 479.0f);
        float hid[16];
        #pragma unroll
        for (int j = 0; j < 16; j++) {
            float v = s_eb1[j] + xi * s_ew1[j] + gx * s_ew1[16 + j] + gy * s_ew1[32 + j];
            hid[j] = gelu_f(v);
        }
        #pragma unroll
        for (int c = 0; c < 32; c++) {
            float e = s_eb2[c];
            #pragma unroll
            for (int j = 0; j < 16; j++) e += hid[j] * s_ew2[j * 32 + c];
            float a = __bfloat162float(Abase[(size_t)c * PLANE + w]);
            G[c][w] = __float2bfloat16(e * a);
        }
    }
    __syncthreads();
    int wv = tid >> 6, lane = tid & 63;
    int arow_lo = lane & 15;
    int kofs = (lane >> 4) << 3;
    for (int t = wv; t < 6; t += 4) {
        int mt = t & 1, nt = t >> 1;
        f32x4 acc = {0.f, 0.f, 0.f, 0.f};
        int arow = mt * 16 + arow_lo;
        #pragma unroll
        for (int kt = 0; kt < 15; kt++) {
            bf16x8 av = *reinterpret_cast<const bf16x8*>(&G[arow][kt * 32 + kofs]);
            bf16x8 bv = *reinterpret_cast<const bf16x8*>(Twig + (((kt * 3 + nt) << 9) + lane * 8));
            acc = __builtin_amdgcn_mfma_f32_16x16x32_bf16(av, bv, acc, 0, 0, 0);
        }
        int n = nt * 16 + (lane & 15);
        if (n < 40) {
            int ky = n >> 1, part = n & 1;
            int crow = mt * 16 + ((lane >> 4) << 2);
            #pragma unroll
            for (int r = 0; r < 4; r++) {
                int c = crow + r;
                Y1[((((size_t)(b * 32 + c)) * WND + ky) * HD + h) * 2 + part] =
                    __float2bfloat16(acc[r]);
            }
        }
    }
}

// F2 as MFMA GEMM: M=1280 rows (bc*20+ky, 960 contiguous bf16 each in Y1),
// K=960, N=80. One wave per (M-tile, N-tile); 30 K-step MFMAs.
__global__ void __launch_bounds__(256) k_F2m(
    const __hip_bfloat16* Y1, const __hip_bfloat16* Tf2, float* Y2)
{
    int wv = threadIdx.x >> 6, lane = threadIdx.x & 63;
    int task = blockIdx.x * 4 + wv;          // < 400
    int mt = task / 5, nt = task % 5;
    int row = mt * 16 + (lane & 15);
    int koff = (lane >> 4) << 3;
    const __hip_bfloat16* arow = Y1 + (size_t)row * 960 + koff;
    f32x4 acc = {0.f, 0.f, 0.f, 0.f};
    #pragma unroll
    for (int kt = 0; kt < 30; kt++) {
        bf16x8 av = *reinterpret_cast<const bf16x8*>(arow + kt * 32);
        bf16x8 bv = *reinterpret_cast<const bf16x8*>(Tf2 + (((kt * 5 + nt) << 9) + lane * 8));
        acc = __builtin_amdgcn_mfma_f32_16x16x32_bf16(av, bv, acc, 0, 0, 0);
    }
    int n = nt * 16 + (lane & 15);
    int mb = mt * 16 + ((lane >> 4) << 2);
    #pragma unroll
    for (int r = 0; r < 4; r++)
        Y2[(size_t)(mb + r) * 80 + n] = acc[r];
}

// Channel mixing; writes Zb as bf16 rows [m][96] (pitch 96, cols 80..95 zero)
// so k_I1m can read aligned bf16x8 A-fragments.
__global__ void __launch_bounds__(256) k_mix(
    const float* Y2, __hip_bfloat16* Zb,
    const float* fw1, const float* fw2, int l)
{
    int gid = blockIdx.x * 256 + threadIdx.x;  // < 122880 = 1280*96
    int col = gid % 96;
    int row = gid / 96;                        // (b*32+oc)*20+ky
    if (col >= 80) { Zb[gid] = __float2bfloat16(0.0f); return; }
    int ky = row % 20;
    int oc = (row / 20) % 32;
    int b = row / 640;
    int z = col & 1;
    int kxi = col >> 1;
    const float* wp;
    int x;
    if (kxi < 20) { wp = fw1; x = kxi; } else { wp = fw2; x = kxi - 20; }
    size_t wbase = ((((size_t)(l * 32) * 32 + oc) * 20 + x) * 20 + ky) * 2 + z;
    const float* y2 = Y2 + ((size_t)b * 32 * 20 + ky) * 80 + kxi * 2 + z;
    float acc = 0.f;
    for (int i = 0; i < 32; i++) {
        float yv = y2[(size_t)i * 1600];
        float wv = wp[wbase + (size_t)i * 25600];
        acc += yv * wv;
    }
    Zb[gid] = __float2bfloat16(acc);
}

// I1 as MFMA GEMM: M=1280 rows (b,oc,ky), K=96 (kxi,re/im pad), N=960 (h,re/im).
// U written as bf16 rows of 960 == existing ((b*32+oc)*20+ky)*480 bf162 layout.
__global__ void __launch_bounds__(256) k_I1m(
    const __hip_bfloat16* Zb, const __hip_bfloat16* Ti1, __hip_bfloat16* U)
{
    int wv = threadIdx.x >> 6, lane = threadIdx.x & 63;
    int task = blockIdx.x * 4 + wv;          // < 4800
    int mt = task / 60, nt = task % 60;
    int row = mt * 16 + (lane & 15);
    int koff = (lane >> 4) << 3;
    const __hip_bfloat16* arow = Zb + (size_t)row * 96 + koff;
    f32x4 acc = {0.f, 0.f, 0.f, 0.f};
    #pragma unroll
    for (int kt = 0; kt < 3; kt++) {
        bf16x8 av = *reinterpret_cast<const bf16x8*>(arow + kt * 32);
        bf16x8 bv = *reinterpret_cast<const bf16x8*>(Ti1 + (((nt * 3 + kt) << 9) + lane * 8));
        acc = __builtin_amdgcn_mfma_f32_16x16x32_bf16(av, bv, acc, 0, 0, 0);
    }
    int n = nt * 16 + (lane & 15);
    int mb = mt * 16 + ((lane >> 4) << 2);
    #pragma unroll
    for (int r = 0; r < 4; r++)
        U[(size_t)(mb + r) * 960 + n] = __float2bfloat16(acc[r]);
}

// I2: fused (inverse ky-DFT + 1x1 conv + bias + gelu) as one MFMA GEMM
// (round-6 version: cooperative LDS operand staging, 30KB LDS, in-place A).
__global__ void __launch_bounds__(256) k_I2(
    const __hip_bfloat16* U, __hip_bfloat16* A,
    const float* convw, const float* convb,
    const __hip_bfloat16* TinvF,
    int l, int do_gelu)
{
    __shared__ __align__(16) __hip_bfloat16 sBf[30 * 512];
    __shared__ __align__(16) __hip_bfloat16 sUf[4 * 512];
    __shared__ __align__(16) __hip_bfloat16 sWf[2 * 512];
    __shared__ float sB[CD];
    int tid = threadIdx.x;
    int b = blockIdx.x / HD;
    int h = blockIdx.x % HD;
    if (tid < CD) sB[tid] = convb[l * CD + tid];
    for (int t = tid; t < 2048; t += 256) {
        int j = t & 7, lane = (t >> 3) & 63, ktmt = t >> 9;
        int mt = ktmt >> 1, kt = ktmt & 1;
        int oc = mt * 16 + (lane & 15);
        int kk = kt * 32 + ((lane >> 4) << 3) + j;
        float v = 0.f;
        if (kk < 40) {
            int ky = kk >> 1;
            __hip_bfloat162 u = reinterpret_cast<const __hip_bfloat162*>(U)
                [(((size_t)b * CD + oc) * WND + ky) * HD + h];
            float sc = (ky == 0 ? 1.0f : 2.0f) * (1.0f / 250000.0f);
            v = ((kk & 1) ? __bfloat162float(u.y) : __bfloat162float(u.x)) * sc;
        }
        sUf[t] = __float2bfloat16(v);
    }
    for (int t = tid; t < 1024; t += 256) {
        int j = t & 7, lane = (t >> 3) & 63, mt = t >> 9;
        int oc = mt * 16 + (lane & 15);
        int ic = ((lane >> 4) << 3) + j;
        sWf[t] = __float2bfloat16(convw[(size_t)l * CD * CD + oc * CD + ic]);
    }
    {
        const unsigned short* Ab = reinterpret_cast<const unsigned short*>(
            A + (size_t)b * CD * PLANE + (size_t)h * WD);
        for (int w = tid; w < WD; w += 256) {
            unsigned short vals[32];
            #pragma unroll
            for (int ic = 0; ic < 32; ic++)
                vals[ic] = Ab[(size_t)ic * PLANE + w];
            int nt = w >> 4, lw = w & 15;
            #pragma unroll
            for (int q = 0; q < 4; q++) {
                uint4 pk;
                pk.x = (unsigned)vals[8 * q + 0] | ((unsigned)vals[8 * q + 1] << 16);
                pk.y = (unsigned)vals[8 * q + 2] | ((unsigned)vals[8 * q + 3] << 16);
                pk.z = (unsigned)vals[8 * q + 4] | ((unsigned)vals[8 * q + 5] << 16);
                pk.w = (unsigned)vals[8 * q + 6] | ((unsigned)vals[8 * q + 7] << 16);
                *reinterpret_cast<uint4*>(&sBf[(nt << 9) + (((q << 4) | lw) << 3)]) = pk;
            }
        }
    }
    __syncthreads();
    int wv = tid >> 6, lane = tid & 63;
    for (int t = wv; t < 60; t += 4) {
        int mt = t & 1, nt = t >> 1;
        f32x4 acc = {0.f, 0.f, 0.f, 0.f};
        #pragma unroll
        for (int kt = 0; kt < 2; kt++) {
            bf16x8 av = *reinterpret_cast<const bf16x8*>(&sUf[((mt * 2 + kt) << 9) + lane * 8]);
            bf16x8 bv = *reinterpret_cast<const bf16x8*>(TinvF + (((nt * 2 + kt) << 9) + lane * 8));
            acc = __builtin_amdgcn_mfma_f32_16x16x32_bf16(av, bv, acc, 0, 0, 0);
        }
        bf16x8 av2 = *reinterpret_cast<const bf16x8*>(&sWf[(mt << 9) + lane * 8]);
        bf16x8 bv2 = *reinterpret_cast<const bf16x8*>(&sBf[(nt << 9) + lane * 8]);
        acc = __builtin_amdgcn_mfma_f32_16x16x32_bf16(av2, bv2, acc, 0, 0, 0);
        int w = nt * 16 + (lane & 15);
        int ocb = mt * 16 + ((lane >> 4) << 2);
        #pragma unroll
        for (int r = 0; r < 4; r++) {
            float v = acc[r] + sB[ocb + r];
            if (do_gelu) v = gelu_f(v);
            A[((size_t)b * CD + (ocb + r)) * PLANE + (size_t)h * WD + w] = __float2bfloat16(v);
        }
    }
}

// Final: proj MLP + 3x3 mask conv + field*mask + pred.
__global__ void __launch_bounds__(256) k_out(
    const __hip_bfloat16* Afin, const float* inp, const float* src,
    const float* pw1, const float* pb1,
    const float* pw2, const float* pb2,
    const float* mw, const float* mb,
    float* out)
{
    __shared__ float sW1[CD * HALFD], sB1[HALFD], sW2[HALFD * 2], sB2[2], sM[9], sMB[1];
    int tid = threadIdx.x;
    for (int t = tid; t < CD * HALFD; t += 256) sW1[t] = pw1[t];
    if (tid < 16) sB1[tid] = pb1[tid];
    if (tid >= 32 && tid < 64) sW2[tid - 32] = pw2[tid - 32];
    if (tid >= 64 && tid < 66) sB2[tid - 64] = pb2[tid - 64];
    if (tid >= 96 && tid < 105) sM[tid - 96] = mw[tid - 96];
    if (tid == 128) sMB[0] = mb[0];
    __syncthreads();
    int gid = blockIdx.x * 256 + tid;  // < 460800
    int b = gid / PLANE;
    int r = gid % PLANE;
    int h = r / WD, w = r % WD;
    const __hip_bfloat16* ap = Afin + (size_t)b * CD * PLANE + r;
    float av[32];
    #pragma unroll
    for (int i = 0; i < 32; i++) av[i] = __bfloat162float(ap[(size_t)i * PLANE]);
    float hid[16];
    #pragma unroll
    for (int j = 0; j < 16; j++) {
        float v = sB1[j];
        #pragma unroll
        for (int i = 0; i < 32; i++) v += av[i] * sW1[i * 16 + j];
        hid[j] = gelu_f(v);
    }
    float p0 = sB2[0], p1 = sB2[1];
    #pragma unroll
    for (int j = 0; j < 16; j++) { p0 += hid[j] * sW2[j * 2]; p1 += hid[j] * sW2[j * 2 + 1]; }
    float m = sMB[0];
    #pragma unroll
    for (int dh = 0; dh < 3; dh++) {
        int hh = h + dh - 1;
        #pragma unroll
        for (int dw = 0; dw < 3; dw++) {
            int ww = w + dw - 1;
            if (hh >= 0 && hh < HD && ww >= 0 && ww < WD)
                m += inp[(size_t)b * PLANE + (size_t)hh * WD + ww] * sM[dh * 3 + dw];
        }
    }
    float f0 = src[(size_t)gid * 3 + 1];
    float f1 = src[(size_t)gid * 3 + 2];
    out[(size_t)gid * 2 + 0] = f0 * m + p0;
    out[(size_t)gid * 2 + 1] = f1 * m + p1;
}

extern "C" void kernel_launch(void* const* d_in, const int* in_sizes, int n_in,
                              void* d_out, int out_size, void* d_ws, size_t ws_size,
                              hipStream_t stream) {
    const float* inp = (const float*)d_in[0];
    const float* src = (const float*)d_in[1];
    const float* iw1 = (const float*)d_in[2];
    const float* ib1 = (const float*)d_in[3];
    const float* iw2 = (const float*)d_in[4];
    const float* ib2 = (const float*)d_in[5];
    const float* ew1 = (const float*)d_in[6];
    const float* eb1 = (const float*)d_in[7];
    const float* ew2 = (const float*)d_in[8];
    const float* eb2 = (const float*)d_in[9];
    const float* fw1 = (const float*)d_in[10];
    const float* fw2 = (const float*)d_in[11];
    const float* cw  = (const float*)d_in[12];
    const float* cb  = (const float*)d_in[13];
    const float* pw1 = (const float*)d_in[14];
    const float* pb1 = (const float*)d_in[15];
    const float* pw2 = (const float*)d_in[16];
    const float* pb2 = (const float*)d_in[17];
    const float* mw  = (const float*)d_in[18];
    const float* mb  = (const float*)d_in[19];

    // Workspace (~33.0 MB):
    //   A bf16 | Y1U bf16 (Y1<->U aliased) | Y2 f32 [1280][80]
    //   | Zb bf16 [1280][96] | Twig | TinvF | Tf2 | Ti1 fragment tables
    const size_t NA = (size_t)BD * CD * PLANE;
    __hip_bfloat16* A   = (__hip_bfloat16*)d_ws;
    __hip_bfloat16* Y1U = A + NA;
    float* Y2 = (float*)(Y1U + (size_t)BD * CD * WND * HD * 2);
    __hip_bfloat16* Zb = (__hip_bfloat16*)(Y2 + 1280 * 80);
    __hip_bfloat16* Twig  = Zb + 1280 * 96;
    __hip_bfloat16* TinvF = Twig + 45 * 512;
    __hip_bfloat16* Tf2   = TinvF + 60 * 512;
    __hip_bfloat16* Ti1   = Tf2 + 150 * 512;

    k_twig<<<90, 256, 0, stream>>>(Twig);
    k_tinv<<<120, 256, 0, stream>>>(TinvF);
    k_tf2<<<300, 256, 0, stream>>>(Tf2);
    k_ti1<<<360, 256, 0, stream>>>(Ti1);
    k_ae<<<1800, 256, 0, stream>>>(src, iw1, ib1, iw2, ib2, A);

    for (int l = 0; l < 4; l++) {
        k_F1g<<<BD * HD, 256, 0, stream>>>(A, inp, ew1, eb1, ew2, eb2, Twig, Y1U);
        k_F2m<<<100, 256, 0, stream>>>(Y1U, Tf2, Y2);
        k_mix<<<480, 256, 0, stream>>>(Y2, Zb, fw1, fw2, l);
        k_I1m<<<1200, 256, 0, stream>>>(Zb, Ti1, Y1U);
        k_I2<<<BD * HD, 256, 0, stream>>>(Y1U, A, cw, cb, TinvF, l, (l < 3) ? 1 : 0);
    }
    k_out<<<1800, 256, 0, stream>>>(A, inp, src, pw1, pb1, pw2, pb2, mw, mb,
                                    (float*)d_out);
}

// Round 9
// 529.545 us; speedup vs baseline: 1.6316x; 1.1670x over previous
//
#include <hip/hip_runtime.h>
#include <hip/hip_bf16.h>

#define BD 2
#define HD 480
#define WD 480
#define CD 32
#define HALFD 16
#define WND 20
#define NP 500
#define PLANE (HD*WD)
#define TWO_PI_OVER_NP 0.012566370614359172954f  /* 2*pi/500 */

typedef __attribute__((ext_vector_type(8))) short bf16x8;
typedef __attribute__((ext_vector_type(4))) float f32x4;

__device__ __forceinline__ float gelu_f(float x) {
    return 0.5f * x * (1.0f + erff(x * 0.70710678118654752f));
}
__device__ __forceinline__ float bfbits2f(short s) {
    unsigned u = ((unsigned)(unsigned short)s) << 16;
    return __uint_as_float(u);
}

// Input MLPs: a = MLP5->16->32(src,grid) -> A;  also e = MLP3->16->32(inp,grid),
// G = a*e (epilogue-fused, no barriers). Channel-planar bf16 (B,C,H,W).
__global__ void __launch_bounds__(256) k_ae(
    const float* src, const float* inp,
    const float* iw1, const float* ib1,
    const float* iw2, const float* ib2,
    const float* ew1, const float* eb1,
    const float* ew2, const float* eb2,
    __hip_bfloat16* A, __hip_bfloat16* G)
{
    __shared__ float s_iw1[80], s_ib1[16], s_iw2[512], s_ib2[32];
    __shared__ float s_ew1[48], s_eb1[16], s_ew2[512], s_eb2[32];
    int tid = threadIdx.x;
    for (int t = tid; t < 512; t += 256) s_iw2[t] = iw2[t];
    for (int t = tid; t < 512; t += 256) s_ew2[t] = ew2[t];
    if (tid < 80) s_iw1[tid] = iw1[tid];
    if (tid >= 96 && tid < 112) s_ib1[tid - 96] = ib1[tid - 96];
    if (tid >= 128 && tid < 160) s_ib2[tid - 128] = ib2[tid - 128];
    if (tid >= 160 && tid < 208) s_ew1[tid - 160] = ew1[tid - 160];
    if (tid >= 208 && tid < 224) s_eb1[tid - 208] = eb1[tid - 208];
    if (tid >= 224 && tid < 256) s_eb2[tid - 224] = eb2[tid - 224];
    __syncthreads();
    int gid = blockIdx.x * 256 + tid;  // < 460800
    int b = gid / PLANE;
    int r = gid % PLANE;
    int h = r / WD, w = r % WD;
    float gx = (float)h * (1.0f / 479.0f);
    float gy = (float)w * (1.0f / 479.0f);
    float s0 = src[(size_t)gid * 3 + 0];
    float s1 = src[(size_t)gid * 3 + 1];
    float s2 = src[(size_t)gid * 3 + 2];
    float hid[16];
    #pragma unroll
    for (int j = 0; j < 16; j++) {
        float v = s_ib1[j] + s0 * s_iw1[j] + s1 * s_iw1[16 + j] + s2 * s_iw1[32 + j]
                + gx * s_iw1[48 + j] + gy * s_iw1[64 + j];
        hid[j] = gelu_f(v);
    }
    float av[32];
    __hip_bfloat16* Ap = A + (size_t)b * CD * PLANE + r;
    for (int c = 0; c < 32; c++) {
        float v = s_ib2[c];
        #pragma unroll
        for (int j = 0; j < 16; j++) v += hid[j] * s_iw2[j * 32 + c];
        av[c] = v;
        Ap[(size_t)c * PLANE] = __float2bfloat16(v);
    }
    // e-MLP + G = a*e
    float xi = inp[gid];
    #pragma unroll
    for (int j = 0; j < 16; j++) {
        float v = s_eb1[j] + xi * s_ew1[j] + gx * s_ew1[16 + j] + gy * s_ew1[32 + j];
        hid[j] = gelu_f(v);
    }
    __hip_bfloat16* Gp = G + (size_t)b * CD * PLANE + r;
    for (int c = 0; c < 32; c++) {
        float e = s_eb2[c];
        #pragma unroll
        for (int j = 0; j < 16; j++) e += hid[j] * s_ew2[j * 32 + c];
        Gp[(size_t)c * PLANE] = __float2bfloat16(av[c] * e);
    }
}

// Swizzled bf16 twiddle fragments for the F1 row-DFT GEMM (K=480, N=48 pad).
__global__ void k_twig(__hip_bfloat16* Twig) {
    int e = blockIdx.x * 256 + threadIdx.x;   // < 45*512
    if (e >= 45 * 512) return;
    int tile = e >> 9, r = e & 511;
    int lane = r >> 3, j = r & 7;
    int kt = tile / 3, nt = tile % 3;
    int k = kt * 32 + ((lane >> 4) << 3) + j;
    int n = nt * 16 + (lane & 15);
    float v = 0.0f;
    if (n < 40) {
        int ky = n >> 1;
        int idx = (k * ky) % NP;
        float ang = (float)idx * TWO_PI_OVER_NP;
        v = (n & 1) ? -sinf(ang) : cosf(ang);
    }
    Twig[e] = __float2bfloat16(v);
}

// Swizzled bf16 inverse-twiddle B-fragments for the I2 GEMM (K=64 pad, N=480).
__global__ void k_tinv(__hip_bfloat16* TinvF) {
    int e = blockIdx.x * 256 + threadIdx.x;   // < 60*512
    if (e >= 60 * 512) return;
    int tile = e >> 9, r = e & 511;
    int lane = r >> 3, j = r & 7;
    int nt = tile >> 1, kt = tile & 1;
    int kk = kt * 32 + ((lane >> 4) << 3) + j;
    int w = nt * 16 + (lane & 15);
    float v = 0.0f;
    if (kk < 40) {
        int ky = kk >> 1;
        int idx = (ky * w) % NP;
        float ang = (float)idx * TWO_PI_OVER_NP;
        v = (kk & 1) ? -sinf(ang) : cosf(ang);
    }
    TinvF[e] = __float2bfloat16(v);
}

// Swizzled bf16 B-fragments for the F2 h-DFT GEMM.
__global__ void k_tf2(__hip_bfloat16* Tf2) {
    int e = blockIdx.x * 256 + threadIdx.x;   // < 150*512
    if (e >= 150 * 512) return;
    int tile = e >> 9, r = e & 511;
    int lane = r >> 3, j = r & 7;
    int kt = tile / 5, nt = tile % 5;
    int k = kt * 32 + ((lane >> 4) << 3) + j;
    int n = nt * 16 + (lane & 15);
    int hh = k >> 1, ri = k & 1;
    int kxi = n >> 1, part = n & 1;
    int kx = (kxi < 20) ? kxi : kxi + 460;
    int idx = (kx * hh) % NP;
    float ang = (float)idx * TWO_PI_OVER_NP;
    float c = cosf(ang), s = sinf(ang);
    float v = (part == 0) ? (ri == 0 ? c : s) : (ri == 0 ? -s : c);
    Tf2[e] = __float2bfloat16(v);
}

// Swizzled bf16 B-fragments for the I1 inverse-kx GEMM (K=80 pad 96, N=960).
__global__ void k_ti1(__hip_bfloat16* Ti1) {
    int e = blockIdx.x * 256 + threadIdx.x;   // < 180*512
    if (e >= 180 * 512) return;
    int tile = e >> 9, r = e & 511;
    int lane = r >> 3, j = r & 7;
    int nt = tile / 3, kt = tile % 3;
    int k = kt * 32 + ((lane >> 4) << 3) + j;
    int n = nt * 16 + (lane & 15);
    float v = 0.0f;
    if (k < 80) {
        int kxi = k >> 1, ri = k & 1;
        int hh = n >> 1, part = n & 1;
        int kx = (kxi < 20) ? kxi : kxi + 460;
        int idx = (kx * hh) % NP;
        float ang = (float)idx * TWO_PI_OVER_NP;
        float c = cosf(ang), s = sinf(ang);
        v = (part == 0) ? (ri == 0 ? c : -s) : (ri == 0 ? s : c);
    }
    Ti1[e] = __float2bfloat16(v);
}

// F1 as pure global-operand MFMA GEMM: task = (b,h,mt,nt), A-frags straight
// from G (aligned 16B), B-frags from Twig (L2-hot). No LDS, no barriers.
__global__ void __launch_bounds__(256) k_F1m(
    const __hip_bfloat16* G, const __hip_bfloat16* Twig, __hip_bfloat16* Y1)
{
    int wv = threadIdx.x >> 6, lane = threadIdx.x & 63;
    int task = blockIdx.x * 4 + wv;          // < 5760
    int bh = task / 6, rem = task % 6;
    int mt = rem & 1, nt = rem >> 1;
    int b = bh / HD, h = bh % HD;
    int c = mt * 16 + (lane & 15);
    int koff = (lane >> 4) << 3;
    const __hip_bfloat16* arow = G + ((size_t)(b * 32 + c)) * PLANE + (size_t)h * WD + koff;
    f32x4 acc = {0.f, 0.f, 0.f, 0.f};
    #pragma unroll
    for (int kt = 0; kt < 15; kt++) {
        bf16x8 av = *reinterpret_cast<const bf16x8*>(arow + kt * 32);
        bf16x8 bv = *reinterpret_cast<const bf16x8*>(Twig + (((kt * 3 + nt) << 9) + lane * 8));
        acc = __builtin_amdgcn_mfma_f32_16x16x32_bf16(av, bv, acc, 0, 0, 0);
    }
    int n = nt * 16 + (lane & 15);
    if (n < 40) {
        int ky = n >> 1, part = n & 1;
        int crow = mt * 16 + ((lane >> 4) << 2);
        #pragma unroll
        for (int r = 0; r < 4; r++) {
            int cc = crow + r;
            Y1[((((size_t)(b * 32 + cc)) * WND + ky) * HD + h) * 2 + part] =
                __float2bfloat16(acc[r]);
        }
    }
}

// F2 as MFMA GEMM: M=1280 rows, K=960, N=80.
__global__ void __launch_bounds__(256) k_F2m(
    const __hip_bfloat16* Y1, const __hip_bfloat16* Tf2, float* Y2)
{
    int wv = threadIdx.x >> 6, lane = threadIdx.x & 63;
    int task = blockIdx.x * 4 + wv;          // < 400
    int mt = task / 5, nt = task % 5;
    int row = mt * 16 + (lane & 15);
    int koff = (lane >> 4) << 3;
    const __hip_bfloat16* arow = Y1 + (size_t)row * 960 + koff;
    f32x4 acc = {0.f, 0.f, 0.f, 0.f};
    #pragma unroll
    for (int kt = 0; kt < 30; kt++) {
        bf16x8 av = *reinterpret_cast<const bf16x8*>(arow + kt * 32);
        bf16x8 bv = *reinterpret_cast<const bf16x8*>(Tf2 + (((kt * 5 + nt) << 9) + lane * 8));
        acc = __builtin_amdgcn_mfma_f32_16x16x32_bf16(av, bv, acc, 0, 0, 0);
    }
    int n = nt * 16 + (lane & 15);
    int mb = mt * 16 + ((lane >> 4) << 2);
    #pragma unroll
    for (int r = 0; r < 4; r++)
        Y2[(size_t)(mb + r) * 80 + n] = acc[r];
}

// Channel mixing; writes Zb as bf16 rows [m][96] (cols 80..95 zero).
__global__ void __launch_bounds__(256) k_mix(
    const float* Y2, __hip_bfloat16* Zb,
    const float* fw1, const float* fw2, int l)
{
    int gid = blockIdx.x * 256 + threadIdx.x;  // < 122880
    int col = gid % 96;
    int row = gid / 96;
    if (col >= 80) { Zb[gid] = __float2bfloat16(0.0f); return; }
    int ky = row % 20;
    int oc = (row / 20) % 32;
    int b = row / 640;
    int z = col & 1;
    int kxi = col >> 1;
    const float* wp;
    int x;
    if (kxi < 20) { wp = fw1; x = kxi; } else { wp = fw2; x = kxi - 20; }
    size_t wbase = ((((size_t)(l * 32) * 32 + oc) * 20 + x) * 20 + ky) * 2 + z;
    const float* y2 = Y2 + ((size_t)b * 32 * 20 + ky) * 80 + kxi * 2 + z;
    float acc = 0.f;
    for (int i = 0; i < 32; i++) {
        float yv = y2[(size_t)i * 1600];
        float wv = wp[wbase + (size_t)i * 25600];
        acc += yv * wv;
    }
    Zb[gid] = __float2bfloat16(acc);
}

// I1 as MFMA GEMM: M=1280 rows, K=96 pad, N=960.
__global__ void __launch_bounds__(256) k_I1m(
    const __hip_bfloat16* Zb, const __hip_bfloat16* Ti1, __hip_bfloat16* U)
{
    int wv = threadIdx.x >> 6, lane = threadIdx.x & 63;
    int task = blockIdx.x * 4 + wv;          // < 4800
    int mt = task / 60, nt = task % 60;
    int row = mt * 16 + (lane & 15);
    int koff = (lane >> 4) << 3;
    const __hip_bfloat16* arow = Zb + (size_t)row * 96 + koff;
    f32x4 acc = {0.f, 0.f, 0.f, 0.f};
    #pragma unroll
    for (int kt = 0; kt < 3; kt++) {
        bf16x8 av = *reinterpret_cast<const bf16x8*>(arow + kt * 32);
        bf16x8 bv = *reinterpret_cast<const bf16x8*>(Ti1 + (((nt * 3 + kt) << 9) + lane * 8));
        acc = __builtin_amdgcn_mfma_f32_16x16x32_bf16(av, bv, acc, 0, 0, 0);
    }
    int n = nt * 16 + (lane & 15);
    int mb = mt * 16 + ((lane >> 4) << 2);
    #pragma unroll
    for (int r = 0; r < 4; r++)
        U[(size_t)(mb + r) * 960 + n] = __float2bfloat16(acc[r]);
}

// I2: (inverse ky-DFT + 1x1 conv + bias + gelu) MFMA GEMM, in-place on A.
// Epilogue-fused G = Anew * e for the next layer's F1 (do_g): e-hidden staged
// bf16 in sH during phase 1; e output-layer 16-dot in the epilogue.
__global__ void __launch_bounds__(256) k_I2(
    const __hip_bfloat16* U, __hip_bfloat16* A, __hip_bfloat16* G,
    const float* convw, const float* convb,
    const __hip_bfloat16* TinvF,
    const float* inp,
    const float* ew1, const float* eb1, const float* ew2, const float* eb2,
    int l, int do_gelu, int do_g)
{
    __shared__ __align__(16) __hip_bfloat16 sBf[30 * 512];
    __shared__ __align__(16) __hip_bfloat16 sUf[4 * 512];
    __shared__ __align__(16) __hip_bfloat16 sWf[2 * 512];
    __shared__ __align__(16) __hip_bfloat16 sH[480 * 16];   // e-hidden [w][j]
    __shared__ float s_ew2t[512];                            // ew2 transposed [oc][j]
    __shared__ float s_ew1[48], s_eb1[16], s_eb2[32];
    __shared__ float sB[CD];
    int tid = threadIdx.x;
    int b = blockIdx.x / HD;
    int h = blockIdx.x % HD;
    if (tid < CD) sB[tid] = convb[l * CD + tid];
    for (int t = tid; t < 512; t += 256) {
        int oc = t >> 4, j = t & 15;
        s_ew2t[t] = ew2[j * 32 + oc];
    }
    if (tid >= 64 && tid < 112) s_ew1[tid - 64] = ew1[tid - 64];
    if (tid >= 112 && tid < 128) s_eb1[tid - 112] = eb1[tid - 112];
    if (tid >= 128 && tid < 160) s_eb2[tid - 128] = eb2[tid - 128];
    for (int t = tid; t < 2048; t += 256) {
        int j = t & 7, lane = (t >> 3) & 63, ktmt = t >> 9;
        int mt = ktmt >> 1, kt = ktmt & 1;
        int oc = mt * 16 + (lane & 15);
        int kk = kt * 32 + ((lane >> 4) << 3) + j;
        float v = 0.f;
        if (kk < 40) {
            int ky = kk >> 1;
            __hip_bfloat162 u = reinterpret_cast<const __hip_bfloat162*>(U)
                [(((size_t)b * CD + oc) * WND + ky) * HD + h];
            float sc = (ky == 0 ? 1.0f : 2.0f) * (1.0f / 250000.0f);
            v = ((kk & 1) ? __bfloat162float(u.y) : __bfloat162float(u.x)) * sc;
        }
        sUf[t] = __float2bfloat16(v);
    }
    for (int t = tid; t < 1024; t += 256) {
        int j = t & 7, lane = (t >> 3) & 63, mt = t >> 9;
        int oc = mt * 16 + (lane & 15);
        int ic = ((lane >> 4) << 3) + j;
        sWf[t] = __float2bfloat16(convw[(size_t)l * CD * CD + oc * CD + ic]);
    }
    {
        const unsigned short* Ab = reinterpret_cast<const unsigned short*>(
            A + (size_t)b * CD * PLANE + (size_t)h * WD);
        for (int w = tid; w < WD; w += 256) {
            unsigned short vals[32];
            #pragma unroll
            for (int ic = 0; ic < 32; ic++)
                vals[ic] = Ab[(size_t)ic * PLANE + w];
            int nt = w >> 4, lw = w & 15;
            #pragma unroll
            for (int q = 0; q < 4; q++) {
                uint4 pk;
                pk.x = (unsigned)vals[8 * q + 0] | ((unsigned)vals[8 * q + 1] << 16);
                pk.y = (unsigned)vals[8 * q + 2] | ((unsigned)vals[8 * q + 3] << 16);
                pk.z = (unsigned)vals[8 * q + 4] | ((unsigned)vals[8 * q + 5] << 16);
                pk.w = (unsigned)vals[8 * q + 6] | ((unsigned)vals[8 * q + 7] << 16);
                *reinterpret_cast<uint4*>(&sBf[(nt << 9) + (((q << 4) | lw) << 3)]) = pk;
            }
        }
    }
    if (do_g) {
        float gx = (float)h * (1.0f / 479.0f);
        for (int w = tid; w < WD; w += 256) {
            float xi = inp[(size_t)b * PLANE + (size_t)h * WD + w];
            float gy = (float)w * (1.0f / 479.0f);
            #pragma unroll
            for (int j = 0; j < 16; j++) {
                float v = s_eb1[j] + xi * s_ew1[j] + gx * s_ew1[16 + j] + gy * s_ew1[32 + j];
                sH[w * 16 + j] = __float2bfloat16(gelu_f(v));
            }
        }
    }
    __syncthreads();
    int wv = tid >> 6, lane = tid & 63;
    for (int t = wv; t < 60; t += 4) {
        int mt = t & 1, nt = t >> 1;
        f32x4 acc = {0.f, 0.f, 0.f, 0.f};
        #pragma unroll
        for (int kt = 0; kt < 2; kt++) {
            bf16x8 av = *reinterpret_cast<const bf16x8*>(&sUf[((mt * 2 + kt) << 9) + lane * 8]);
            bf16x8 bv = *reinterpret_cast<const bf16x8*>(TinvF + (((nt * 2 + kt) << 9) + lane * 8));
            acc = __builtin_amdgcn_mfma_f32_16x16x32_bf16(av, bv, acc, 0, 0, 0);
        }
        bf16x8 av2 = *reinterpret_cast<const bf16x8*>(&sWf[(mt << 9) + lane * 8]);
        bf16x8 bv2 = *reinterpret_cast<const bf16x8*>(&sBf[(nt << 9) + lane * 8]);
        acc = __builtin_amdgcn_mfma_f32_16x16x32_bf16(av2, bv2, acc, 0, 0, 0);
        int w = nt * 16 + (lane & 15);
        int ocb = mt * 16 + ((lane >> 4) << 2);
        if (do_g) {
            bf16x8 h0 = *reinterpret_cast<const bf16x8*>(&sH[w * 16]);
            bf16x8 h1 = *reinterpret_cast<const bf16x8*>(&sH[w * 16 + 8]);
            #pragma unroll
            for (int r = 0; r < 4; r++) {
                int oc = ocb + r;
                float v = acc[r] + sB[oc];
                if (do_gelu) v = gelu_f(v);
                A[((size_t)b * CD + oc) * PLANE + (size_t)h * WD + w] = __float2bfloat16(v);
                float e = s_eb2[oc];
                const float* wt = s_ew2t + oc * 16;
                #pragma unroll
                for (int j = 0; j < 8; j++) e += bfbits2f(h0[j]) * wt[j];
                #pragma unroll
                for (int j = 0; j < 8; j++) e += bfbits2f(h1[j]) * wt[8 + j];
                G[((size_t)b * CD + oc) * PLANE + (size_t)h * WD + w] = __float2bfloat16(v * e);
            }
        } else {
            #pragma unroll
            for (int r = 0; r < 4; r++) {
                int oc = ocb + r;
                float v = acc[r] + sB[oc];
                if (do_gelu) v = gelu_f(v);
                A[((size_t)b * CD + oc) * PLANE + (size_t)h * WD + w] = __float2bfloat16(v);
            }
        }
    }
}

// Final: proj MLP + 3x3 mask conv + field*mask + pred.
__global__ void __launch_bounds__(256) k_out(
    const __hip_bfloat16* Afin, const float* inp, const float* src,
    const float* pw1, const float* pb1,
    const float* pw2, const float* pb2,
    const float* mw, const float* mb,
    float* out)
{
    __shared__ float sW1[CD * HALFD], sB1[HALFD], sW2[HALFD * 2], sB2[2], sM[9], sMB[1];
    int tid = threadIdx.x;
    for (int t = tid; t < CD * HALFD; t += 256) sW1[t] = pw1[t];
    if (tid < 16) sB1[tid] = pb1[tid];
    if (tid >= 32 && tid < 64) sW2[tid - 32] = pw2[tid - 32];
    if (tid >= 64 && tid < 66) sB2[tid - 64] = pb2[tid - 64];
    if (tid >= 96 && tid < 105) sM[tid - 96] = mw[tid - 96];
    if (tid == 128) sMB[0] = mb[0];
    __syncthreads();
    int gid = blockIdx.x * 256 + tid;  // < 460800
    int b = gid / PLANE;
    int r = gid % PLANE;
    int h = r / WD, w = r % WD;
    const __hip_bfloat16* ap = Afin + (size_t)b * CD * PLANE + r;
    float av[32];
    #pragma unroll
    for (int i = 0; i < 32; i++) av[i] = __bfloat162float(ap[(size_t)i * PLANE]);
    float hid[16];
    #pragma unroll
    for (int j = 0; j < 16; j++) {
        float v = sB1[j];
        #pragma unroll
        for (int i = 0; i < 32; i++) v += av[i] * sW1[i * 16 + j];
        hid[j] = gelu_f(v);
    }
    float p0 = sB2[0], p1 = sB2[1];
    #pragma unroll
    for (int j = 0; j < 16; j++) { p0 += hid[j] * sW2[j * 2]; p1 += hid[j] * sW2[j * 2 + 1]; }
    float m = sMB[0];
    #pragma unroll
    for (int dh = 0; dh < 3; dh++) {
        int hh = h + dh - 1;
        #pragma unroll
        for (int dw = 0; dw < 3; dw++) {
            int ww = w + dw - 1;
            if (hh >= 0 && hh < HD && ww >= 0 && ww < WD)
                m += inp[(size_t)b * PLANE + (size_t)hh * WD + ww] * sM[dh * 3 + dw];
        }
    }
    float f0 = src[(size_t)gid * 3 + 1];
    float f1 = src[(size_t)gid * 3 + 2];
    out[(size_t)gid * 2 + 0] = f0 * m + p0;
    out[(size_t)gid * 2 + 1] = f1 * m + p1;
}

extern "C" void kernel_launch(void* const* d_in, const int* in_sizes, int n_in,
                              void* d_out, int out_size, void* d_ws, size_t ws_size,
                              hipStream_t stream) {
    const float* inp = (const float*)d_in[0];
    const float* src = (const float*)d_in[1];
    const float* iw1 = (const float*)d_in[2];
    const float* ib1 = (const float*)d_in[3];
    const float* iw2 = (const float*)d_in[4];
    const float* ib2 = (const float*)d_in[5];
    const float* ew1 = (const float*)d_in[6];
    const float* eb1 = (const float*)d_in[7];
    const float* ew2 = (const float*)d_in[8];
    const float* eb2 = (const float*)d_in[9];
    const float* fw1 = (const float*)d_in[10];
    const float* fw2 = (const float*)d_in[11];
    const float* cw  = (const float*)d_in[12];
    const float* cb  = (const float*)d_in[13];
    const float* pw1 = (const float*)d_in[14];
    const float* pb1 = (const float*)d_in[15];
    const float* pw2 = (const float*)d_in[16];
    const float* pb2 = (const float*)d_in[17];
    const float* mw  = (const float*)d_in[18];
    const float* mb  = (const float*)d_in[19];

    // Workspace (~62.6 MB):
    //   A bf16 29.49 MB | G bf16 29.49 MB (g = a*e, for the F1 GEMM)
    //   | Y1U bf16 2.46 MB (Y1<->U aliased) | Y2 f32 0.41 MB | Zb bf16 0.25 MB
    //   | Twig | TinvF | Tf2 | Ti1 fragment tables (~0.45 MB)
    const size_t NA = (size_t)BD * CD * PLANE;
    __hip_bfloat16* A   = (__hip_bfloat16*)d_ws;
    __hip_bfloat16* G   = A + NA;
    __hip_bfloat16* Y1U = G + NA;
    float* Y2 = (float*)(Y1U + (size_t)BD * CD * WND * HD * 2);
    __hip_bfloat16* Zb = (__hip_bfloat16*)(Y2 + 1280 * 80);
    __hip_bfloat16* Twig  = Zb + 1280 * 96;
    __hip_bfloat16* TinvF = Twig + 45 * 512;
    __hip_bfloat16* Tf2   = TinvF + 60 * 512;
    __hip_bfloat16* Ti1   = Tf2 + 150 * 512;

    k_twig<<<90, 256, 0, stream>>>(Twig);
    k_tinv<<<120, 256, 0, stream>>>(TinvF);
    k_tf2<<<300, 256, 0, stream>>>(Tf2);
    k_ti1<<<360, 256, 0, stream>>>(Ti1);
    k_ae<<<1800, 256, 0, stream>>>(src, inp, iw1, ib1, iw2, ib2,
                                   ew1, eb1, ew2, eb2, A, G);

    for (int l = 0; l < 4; l++) {
        k_F1m<<<1440, 256, 0, stream>>>(G, Twig, Y1U);
        k_F2m<<<100, 256, 0, stream>>>(Y1U, Tf2, Y2);
        k_mix<<<480, 256, 0, stream>>>(Y2, Zb, fw1, fw2, l);
        k_I1m<<<1200, 256, 0, stream>>>(Zb, Ti1, Y1U);
        k_I2<<<BD * HD, 256, 0, stream>>>(Y1U, A, G, cw, cb, TinvF,
                                          inp, ew1, eb1, ew2, eb2,
                                          l, (l < 3) ? 1 : 0, (l < 3) ? 1 : 0);
    }
    k_out<<<1800, 256, 0, stream>>>(A, inp, src, pw1, pb1, pw2, pb2, mw, mb,
                                    (float*)d_out);
}

// Round 10
// 454.280 us; speedup vs baseline: 1.9019x; 1.1657x over previous
//
#include <hip/hip_runtime.h>
#include <hip/hip_bf16.h>

#define BD 2
#define HD 480
#define WD 480
#define CD 32
#define HALFD 16
#define WND 20
#define NP 500
#define PLANE (HD*WD)
#define TWO_PI_OVER_NP 0.012566370614359172954f  /* 2*pi/500 */

typedef __attribute__((ext_vector_type(8))) short bf16x8;
typedef __attribute__((ext_vector_type(4))) float f32x4;

__device__ __forceinline__ float gelu_f(float x) {
    return 0.5f * x * (1.0f + erff(x * 0.70710678118654752f));
}
__device__ __forceinline__ float bfbits2f(short s) {
    unsigned u = ((unsigned)(unsigned short)s) << 16;
    return __uint_as_float(u);
}
__device__ __forceinline__ short bf16s(float v) {
    __hip_bfloat16 b = __float2bfloat16(v);
    return *reinterpret_cast<short*>(&b);
}

// Input MLPs: a = MLP5->16->32(src,grid) -> A;  e = MLP3->16->32(inp,grid) -> E.
// e is LAYER-INVARIANT, so E is materialized once and reused by every k_F1m.
__global__ void __launch_bounds__(256) k_ae(
    const float* src, const float* inp,
    const float* iw1, const float* ib1,
    const float* iw2, const float* ib2,
    const float* ew1, const float* eb1,
    const float* ew2, const float* eb2,
    __hip_bfloat16* A, __hip_bfloat16* E)
{
    __shared__ float s_iw1[80], s_ib1[16], s_iw2[512], s_ib2[32];
    __shared__ float s_ew1[48], s_eb1[16], s_ew2[512], s_eb2[32];
    int tid = threadIdx.x;
    for (int t = tid; t < 512; t += 256) s_iw2[t] = iw2[t];
    for (int t = tid; t < 512; t += 256) s_ew2[t] = ew2[t];
    if (tid < 80) s_iw1[tid] = iw1[tid];
    if (tid >= 96 && tid < 112) s_ib1[tid - 96] = ib1[tid - 96];
    if (tid >= 128 && tid < 160) s_ib2[tid - 128] = ib2[tid - 128];
    if (tid >= 160 && tid < 208) s_ew1[tid - 160] = ew1[tid - 160];
    if (tid >= 208 && tid < 224) s_eb1[tid - 208] = eb1[tid - 208];
    if (tid >= 224 && tid < 256) s_eb2[tid - 224] = eb2[tid - 224];
    __syncthreads();
    int gid = blockIdx.x * 256 + tid;  // < 460800
    int b = gid / PLANE;
    int r = gid % PLANE;
    int h = r / WD, w = r % WD;
    float gx = (float)h * (1.0f / 479.0f);
    float gy = (float)w * (1.0f / 479.0f);
    float s0 = src[(size_t)gid * 3 + 0];
    float s1 = src[(size_t)gid * 3 + 1];
    float s2 = src[(size_t)gid * 3 + 2];
    float hid[16];
    #pragma unroll
    for (int j = 0; j < 16; j++) {
        float v = s_ib1[j] + s0 * s_iw1[j] + s1 * s_iw1[16 + j] + s2 * s_iw1[32 + j]
                + gx * s_iw1[48 + j] + gy * s_iw1[64 + j];
        hid[j] = gelu_f(v);
    }
    __hip_bfloat16* Ap = A + (size_t)b * CD * PLANE + r;
    for (int c = 0; c < 32; c++) {
        float v = s_ib2[c];
        #pragma unroll
        for (int j = 0; j < 16; j++) v += hid[j] * s_iw2[j * 32 + c];
        Ap[(size_t)c * PLANE] = __float2bfloat16(v);
    }
    float xi = inp[gid];
    #pragma unroll
    for (int j = 0; j < 16; j++) {
        float v = s_eb1[j] + xi * s_ew1[j] + gx * s_ew1[16 + j] + gy * s_ew1[32 + j];
        hid[j] = gelu_f(v);
    }
    __hip_bfloat16* Ep = E + (size_t)b * CD * PLANE + r;
    for (int c = 0; c < 32; c++) {
        float e = s_eb2[c];
        #pragma unroll
        for (int j = 0; j < 16; j++) e += hid[j] * s_ew2[j * 32 + c];
        Ep[(size_t)c * PLANE] = __float2bfloat16(e);
    }
}

// All four swizzled twiddle fragment tables in one kernel (they are laid out
// contiguously in ws): Twig[0,45) | TinvF[45,105) | Tf2[105,255) | Ti1[255,435).
__global__ void k_tables(__hip_bfloat16* T) {
    int e = blockIdx.x * 256 + threadIdx.x;   // < 435*512
    if (e >= 435 * 512) return;
    int tile = e >> 9, r = e & 511;
    int lane = r >> 3, j = r & 7;
    float v = 0.0f;
    if (tile < 45) {                       // Twig: F1 row-DFT (K=480, N=48 pad)
        int kt = tile / 3, nt = tile % 3;
        int k = kt * 32 + ((lane >> 4) << 3) + j;
        int n = nt * 16 + (lane & 15);
        if (n < 40) {
            int ky = n >> 1;
            int idx = (k * ky) % NP;
            float ang = (float)idx * TWO_PI_OVER_NP;
            v = (n & 1) ? -sinf(ang) : cosf(ang);
        }
    } else if (tile < 105) {               // TinvF: I2 inverse-ky (K=64 pad, N=480)
        int t2 = tile - 45;
        int nt = t2 >> 1, kt = t2 & 1;
        int kk = kt * 32 + ((lane >> 4) << 3) + j;
        int w = nt * 16 + (lane & 15);
        if (kk < 40) {
            int ky = kk >> 1;
            int idx = (ky * w) % NP;
            float ang = (float)idx * TWO_PI_OVER_NP;
            v = (kk & 1) ? -sinf(ang) : cosf(ang);
        }
    } else if (tile < 255) {               // Tf2: F2 h-DFT (K=960, N=80)
        int t2 = tile - 105;
        int kt = t2 / 5, nt = t2 % 5;
        int k = kt * 32 + ((lane >> 4) << 3) + j;
        int n = nt * 16 + (lane & 15);
        int hh = k >> 1, ri = k & 1;
        int kxi = n >> 1, part = n & 1;
        int kx = (kxi < 20) ? kxi : kxi + 460;
        int idx = (kx * hh) % NP;
        float ang = (float)idx * TWO_PI_OVER_NP;
        float c = cosf(ang), s = sinf(ang);
        v = (part == 0) ? (ri == 0 ? c : s) : (ri == 0 ? -s : c);
    } else {                               // Ti1: I1 inverse-kx (K=96 pad, N=960)
        int t2 = tile - 255;
        int nt = t2 / 3, kt = t2 % 3;
        int k = kt * 32 + ((lane >> 4) << 3) + j;
        int n = nt * 16 + (lane & 15);
        if (k < 80) {
            int kxi = k >> 1, ri = k & 1;
            int hh = n >> 1, part = n & 1;
            int kx = (kxi < 20) ? kxi : kxi + 460;
            int idx = (kx * hh) % NP;
            float ang = (float)idx * TWO_PI_OVER_NP;
            float c = cosf(ang), s = sinf(ang);
            v = (part == 0) ? (ri == 0 ? c : -s) : (ri == 0 ? s : c);
        }
    }
    T[e] = __float2bfloat16(v);
}

// F1 as pure global-operand MFMA GEMM; the A-fragment is formed on the fly as
// A ⊙ E (both contiguous in w, aligned 16B loads). No LDS, no barriers.
__global__ void __launch_bounds__(256) k_F1m(
    const __hip_bfloat16* A, const __hip_bfloat16* E,
    const __hip_bfloat16* Twig, __hip_bfloat16* Y1)
{
    int wv = threadIdx.x >> 6, lane = threadIdx.x & 63;
    int task = blockIdx.x * 4 + wv;          // < 5760
    int bh = task / 6, rem = task % 6;
    int mt = rem & 1, nt = rem >> 1;
    int b = bh / HD, h = bh % HD;
    int c = mt * 16 + (lane & 15);
    int koff = (lane >> 4) << 3;
    size_t base = ((size_t)(b * 32 + c)) * PLANE + (size_t)h * WD + koff;
    const __hip_bfloat16* arow = A + base;
    const __hip_bfloat16* erow = E + base;
    f32x4 acc = {0.f, 0.f, 0.f, 0.f};
    #pragma unroll
    for (int kt = 0; kt < 15; kt++) {
        bf16x8 av = *reinterpret_cast<const bf16x8*>(arow + kt * 32);
        bf16x8 ev = *reinterpret_cast<const bf16x8*>(erow + kt * 32);
        bf16x8 gv;
        #pragma unroll
        for (int j = 0; j < 8; j++)
            gv[j] = bf16s(bfbits2f(av[j]) * bfbits2f(ev[j]));
        bf16x8 bv = *reinterpret_cast<const bf16x8*>(Twig + (((kt * 3 + nt) << 9) + lane * 8));
        acc = __builtin_amdgcn_mfma_f32_16x16x32_bf16(gv, bv, acc, 0, 0, 0);
    }
    int n = nt * 16 + (lane & 15);
    if (n < 40) {
        int ky = n >> 1, part = n & 1;
        int crow = mt * 16 + ((lane >> 4) << 2);
        #pragma unroll
        for (int r = 0; r < 4; r++) {
            int cc = crow + r;
            Y1[((((size_t)(b * 32 + cc)) * WND + ky) * HD + h) * 2 + part] =
                __float2bfloat16(acc[r]);
        }
    }
}

// F2 as MFMA GEMM: M=1280 rows, K=960, N=80.
__global__ void __launch_bounds__(256) k_F2m(
    const __hip_bfloat16* Y1, const __hip_bfloat16* Tf2, float* Y2)
{
    int wv = threadIdx.x >> 6, lane = threadIdx.x & 63;
    int task = blockIdx.x * 4 + wv;          // < 400
    int mt = task / 5, nt = task % 5;
    int row = mt * 16 + (lane & 15);
    int koff = (lane >> 4) << 3;
    const __hip_bfloat16* arow = Y1 + (size_t)row * 960 + koff;
    f32x4 acc = {0.f, 0.f, 0.f, 0.f};
    #pragma unroll
    for (int kt = 0; kt < 30; kt++) {
        bf16x8 av = *reinterpret_cast<const bf16x8*>(arow + kt * 32);
        bf16x8 bv = *reinterpret_cast<const bf16x8*>(Tf2 + (((kt * 5 + nt) << 9) + lane * 8));
        acc = __builtin_amdgcn_mfma_f32_16x16x32_bf16(av, bv, acc, 0, 0, 0);
    }
    int n = nt * 16 + (lane & 15);
    int mb = mt * 16 + ((lane >> 4) << 2);
    #pragma unroll
    for (int r = 0; r < 4; r++)
        Y2[(size_t)(mb + r) * 80 + n] = acc[r];
}

// Channel mixing; writes Zb as bf16 rows [m][96] (cols 80..95 zero).
__global__ void __launch_bounds__(256) k_mix(
    const float* Y2, __hip_bfloat16* Zb,
    const float* fw1, const float* fw2, int l)
{
    int gid = blockIdx.x * 256 + threadIdx.x;  // < 122880
    int col = gid % 96;
    int row = gid / 96;
    if (col >= 80) { Zb[gid] = __float2bfloat16(0.0f); return; }
    int ky = row % 20;
    int oc = (row / 20) % 32;
    int b = row / 640;
    int z = col & 1;
    int kxi = col >> 1;
    const float* wp;
    int x;
    if (kxi < 20) { wp = fw1; x = kxi; } else { wp = fw2; x = kxi - 20; }
    size_t wbase = ((((size_t)(l * 32) * 32 + oc) * 20 + x) * 20 + ky) * 2 + z;
    const float* y2 = Y2 + ((size_t)b * 32 * 20 + ky) * 80 + kxi * 2 + z;
    float acc = 0.f;
    for (int i = 0; i < 32; i++) {
        float yv = y2[(size_t)i * 1600];
        float wv = wp[wbase + (size_t)i * 25600];
        acc += yv * wv;
    }
    Zb[gid] = __float2bfloat16(acc);
}

// I1 as MFMA GEMM: M=1280 rows, K=96 pad, N=960.
__global__ void __launch_bounds__(256) k_I1m(
    const __hip_bfloat16* Zb, const __hip_bfloat16* Ti1, __hip_bfloat16* U)
{
    int wv = threadIdx.x >> 6, lane = threadIdx.x & 63;
    int task = blockIdx.x * 4 + wv;          // < 4800
    int mt = task / 60, nt = task % 60;
    int row = mt * 16 + (lane & 15);
    int koff = (lane >> 4) << 3;
    const __hip_bfloat16* arow = Zb + (size_t)row * 96 + koff;
    f32x4 acc = {0.f, 0.f, 0.f, 0.f};
    #pragma unroll
    for (int kt = 0; kt < 3; kt++) {
        bf16x8 av = *reinterpret_cast<const bf16x8*>(arow + kt * 32);
        bf16x8 bv = *reinterpret_cast<const bf16x8*>(Ti1 + (((nt * 3 + kt) << 9) + lane * 8));
        acc = __builtin_amdgcn_mfma_f32_16x16x32_bf16(av, bv, acc, 0, 0, 0);
    }
    int n = nt * 16 + (lane & 15);
    int mb = mt * 16 + ((lane >> 4) << 2);
    #pragma unroll
    for (int r = 0; r < 4; r++)
        U[(size_t)(mb + r) * 960 + n] = __float2bfloat16(acc[r]);
}

// I2: (inverse ky-DFT + 1x1 conv + bias + gelu) MFMA GEMM, in-place on A.
// Lean round-6 form: 37KB LDS, no G production (k_F1m reads A⊙E directly).
__global__ void __launch_bounds__(256) k_I2(
    const __hip_bfloat16* U, __hip_bfloat16* A,
    const float* convw, const float* convb,
    const __hip_bfloat16* TinvF,
    int l, int do_gelu)
{
    __shared__ __align__(16) __hip_bfloat16 sBf[30 * 512];
    __shared__ __align__(16) __hip_bfloat16 sUf[4 * 512];
    __shared__ __align__(16) __hip_bfloat16 sWf[2 * 512];
    __shared__ float sB[CD];
    int tid = threadIdx.x;
    int b = blockIdx.x / HD;
    int h = blockIdx.x % HD;
    if (tid < CD) sB[tid] = convb[l * CD + tid];
    for (int t = tid; t < 2048; t += 256) {
        int j = t & 7, lane = (t >> 3) & 63, ktmt = t >> 9;
        int mt = ktmt >> 1, kt = ktmt & 1;
        int oc = mt * 16 + (lane & 15);
        int kk = kt * 32 + ((lane >> 4) << 3) + j;
        float v = 0.f;
        if (kk < 40) {
            int ky = kk >> 1;
            __hip_bfloat162 u = reinterpret_cast<const __hip_bfloat162*>(U)
                [(((size_t)b * CD + oc) * WND + ky) * HD + h];
            float sc = (ky == 0 ? 1.0f : 2.0f) * (1.0f / 250000.0f);
            v = ((kk & 1) ? __bfloat162float(u.y) : __bfloat162float(u.x)) * sc;
        }
        sUf[t] = __float2bfloat16(v);
    }
    for (int t = tid; t < 1024; t += 256) {
        int j = t & 7, lane = (t >> 3) & 63, mt = t >> 9;
        int oc = mt * 16 + (lane & 15);
        int ic = ((lane >> 4) << 3) + j;
        sWf[t] = __float2bfloat16(convw[(size_t)l * CD * CD + oc * CD + ic]);
    }
    {
        const unsigned short* Ab = reinterpret_cast<const unsigned short*>(
            A + (size_t)b * CD * PLANE + (size_t)h * WD);
        for (int w = tid; w < WD; w += 256) {
            unsigned short vals[32];
            #pragma unroll
            for (int ic = 0; ic < 32; ic++)
                vals[ic] = Ab[(size_t)ic * PLANE + w];
            int nt = w >> 4, lw = w & 15;
            #pragma unroll
            for (int q = 0; q < 4; q++) {
                uint4 pk;
                pk.x = (unsigned)vals[8 * q + 0] | ((unsigned)vals[8 * q + 1] << 16);
                pk.y = (unsigned)vals[8 * q + 2] | ((unsigned)vals[8 * q + 3] << 16);
                pk.z = (unsigned)vals[8 * q + 4] | ((unsigned)vals[8 * q + 5] << 16);
                pk.w = (unsigned)vals[8 * q + 6] | ((unsigned)vals[8 * q + 7] << 16);
                *reinterpret_cast<uint4*>(&sBf[(nt << 9) + (((q << 4) | lw) << 3)]) = pk;
            }
        }
    }
    __syncthreads();
    int wv = tid >> 6, lane = tid & 63;
    for (int t = wv; t < 60; t += 4) {
        int mt = t & 1, nt = t >> 1;
        f32x4 acc = {0.f, 0.f, 0.f, 0.f};
        #pragma unroll
        for (int kt = 0; kt < 2; kt++) {
            bf16x8 av = *reinterpret_cast<const bf16x8*>(&sUf[((mt * 2 + kt) << 9) + lane * 8]);
            bf16x8 bv = *reinterpret_cast<const bf16x8*>(TinvF + (((nt * 2 + kt) << 9) + lane * 8));
            acc = __builtin_amdgcn_mfma_f32_16x16x32_bf16(av, bv, acc, 0, 0, 0);
        }
        bf16x8 av2 = *reinterpret_cast<const bf16x8*>(&sWf[(mt << 9) + lane * 8]);
        bf16x8 bv2 = *reinterpret_cast<const bf16x8*>(&sBf[(nt << 9) + lane * 8]);
        acc = __builtin_amdgcn_mfma_f32_16x16x32_bf16(av2, bv2, acc, 0, 0, 0);
        int w = nt * 16 + (lane & 15);
        int ocb = mt * 16 + ((lane >> 4) << 2);
        #pragma unroll
        for (int r = 0; r < 4; r++) {
            float v = acc[r] + sB[ocb + r];
            if (do_gelu) v = gelu_f(v);
            A[((size_t)b * CD + (ocb + r)) * PLANE + (size_t)h * WD + w] = __float2bfloat16(v);
        }
    }
}

// Final: proj MLP + 3x3 mask conv + field*mask + pred.
__global__ void __launch_bounds__(256) k_out(
    const __hip_bfloat16* Afin, const float* inp, const float* src,
    const float* pw1, const float* pb1,
    const float* pw2, const float* pb2,
    const float* mw, const float* mb,
    float* out)
{
    __shared__ float sW1[CD * HALFD], sB1[HALFD], sW2[HALFD * 2], sB2[2], sM[9], sMB[1];
    int tid = threadIdx.x;
    for (int t = tid; t < CD * HALFD; t += 256) sW1[t] = pw1[t];
    if (tid < 16) sB1[tid] = pb1[tid];
    if (tid >= 32 && tid < 64) sW2[tid - 32] = pw2[tid - 32];
    if (tid >= 64 && tid < 66) sB2[tid - 64] = pb2[tid - 64];
    if (tid >= 96 && tid < 105) sM[tid - 96] = mw[tid - 96];
    if (tid == 128) sMB[0] = mb[0];
    __syncthreads();
    int gid = blockIdx.x * 256 + tid;  // < 460800
    int b = gid / PLANE;
    int r = gid % PLANE;
    int h = r / WD, w = r % WD;
    const __hip_bfloat16* ap = Afin + (size_t)b * CD * PLANE + r;
    float av[32];
    #pragma unroll
    for (int i = 0; i < 32; i++) av[i] = __bfloat162float(ap[(size_t)i * PLANE]);
    float hid[16];
    #pragma unroll
    for (int j = 0; j < 16; j++) {
        float v = sB1[j];
        #pragma unroll
        for (int i = 0; i < 32; i++) v += av[i] * sW1[i * 16 + j];
        hid[j] = gelu_f(v);
    }
    float p0 = sB2[0], p1 = sB2[1];
    #pragma unroll
    for (int j = 0; j < 16; j++) { p0 += hid[j] * sW2[j * 2]; p1 += hid[j] * sW2[j * 2 + 1]; }
    float m = sMB[0];
    #pragma unroll
    for (int dh = 0; dh < 3; dh++) {
        int hh = h + dh - 1;
        #pragma unroll
        for (int dw = 0; dw < 3; dw++) {
            int ww = w + dw - 1;
            if (hh >= 0 && hh < HD && ww >= 0 && ww < WD)
                m += inp[(size_t)b * PLANE + (size_t)hh * WD + ww] * sM[dh * 3 + dw];
        }
    }
    float f0 = src[(size_t)gid * 3 + 1];
    float f1 = src[(size_t)gid * 3 + 2];
    out[(size_t)gid * 2 + 0] = f0 * m + p0;
    out[(size_t)gid * 2 + 1] = f1 * m + p1;
}

extern "C" void kernel_launch(void* const* d_in, const int* in_sizes, int n_in,
                              void* d_out, int out_size, void* d_ws, size_t ws_size,
                              hipStream_t stream) {
    const float* inp = (const float*)d_in[0];
    const float* src = (const float*)d_in[1];
    const float* iw1 = (const float*)d_in[2];
    const float* ib1 = (const float*)d_in[3];
    const float* iw2 = (const float*)d_in[4];
    const float* ib2 = (const float*)d_in[5];
    const float* ew1 = (const float*)d_in[6];
    const float* eb1 = (const float*)d_in[7];
    const float* ew2 = (const float*)d_in[8];
    const float* eb2 = (const float*)d_in[9];
    const float* fw1 = (const float*)d_in[10];
    const float* fw2 = (const float*)d_in[11];
    const float* cw  = (const float*)d_in[12];
    const float* cb  = (const float*)d_in[13];
    const float* pw1 = (const float*)d_in[14];
    const float* pb1 = (const float*)d_in[15];
    const float* pw2 = (const float*)d_in[16];
    const float* pb2 = (const float*)d_in[17];
    const float* mw  = (const float*)d_in[18];
    const float* mb  = (const float*)d_in[19];

    // Workspace (~62.6 MB):
    //   A bf16 29.49 MB | E bf16 29.49 MB (layer-invariant e)
    //   | Y1U bf16 2.46 MB (Y1<->U aliased) | Y2 f32 0.41 MB | Zb bf16 0.25 MB
    //   | tables bf16 435 tiles x 512 (Twig|TinvF|Tf2|Ti1, contiguous)
    const size_t NA = (size_t)BD * CD * PLANE;
    __hip_bfloat16* A   = (__hip_bfloat16*)d_ws;
    __hip_bfloat16* E   = A + NA;
    __hip_bfloat16* Y1U = E + NA;
    float* Y2 = (float*)(Y1U + (size_t)BD * CD * WND * HD * 2);
    __hip_bfloat16* Zb = (__hip_bfloat16*)(Y2 + 1280 * 80);
    __hip_bfloat16* Tbl   = Zb + 1280 * 96;
    __hip_bfloat16* Twig  = Tbl;
    __hip_bfloat16* TinvF = Twig + 45 * 512;
    __hip_bfloat16* Tf2   = TinvF + 60 * 512;
    __hip_bfloat16* Ti1   = Tf2 + 150 * 512;

    k_tables<<<870, 256, 0, stream>>>(Tbl);
    k_ae<<<1800, 256, 0, stream>>>(src, inp, iw1, ib1, iw2, ib2,
                                   ew1, eb1, ew2, eb2, A, E);

    for (int l = 0; l < 4; l++) {
        k_F1m<<<1440, 256, 0, stream>>>(A, E, Twig, Y1U);
        k_F2m<<<100, 256, 0, stream>>>(Y1U, Tf2, Y2);
        k_mix<<<480, 256, 0, stream>>>(Y2, Zb, fw1, fw2, l);
        k_I1m<<<1200, 256, 0, stream>>>(Zb, Ti1, Y1U);
        k_I2<<<BD * HD, 256, 0, stream>>>(Y1U, A, cw, cb, TinvF, l, (l < 3) ? 1 : 0);
    }
    k_out<<<1800, 256, 0, stream>>>(A, inp, src, pw1, pb1, pw2, pb2, mw, mb,
                                    (float*)d_out);
}